// Round 4
// baseline (653.548 us; speedup 1.0000x reference)
//
#include <hip/hip_runtime.h>
#include <stdint.h>
#include <math.h>

#define IN_C 256
#define HID 128
#define OUT_C 64
#define CHUNK 4096   // edges per chunk; each chunk visited by 8 class-blocks

// ---------------------------------------------------------------------------
// Preprocessing. Classes: dst node ranges, cls = umulhi(d, clsmag) in [0,8).
// blockIdx&7 == class; with round-robin block->XCD dispatch this makes all
// writes/atomics for a class XCD-local (perf heuristic only, not correctness).
// ---------------------------------------------------------------------------

__global__ void init_kernel(int* __restrict__ cnt, float* __restrict__ degf, int n) {
    int i = blockIdx.x * blockDim.x + threadIdx.x;
    if (i < n) { cnt[i] = 1; degf[i] = 1.0f; }   // self-loop
}

__global__ __launch_bounds__(256) void countdeg_kernel(const int* __restrict__ ei,
                                                       const float* __restrict__ ew,
                                                       int* __restrict__ cnt,
                                                       float* __restrict__ degf,
                                                       int e, unsigned clsmag) {
    const unsigned cls = blockIdx.x & 7;
    const int base = (blockIdx.x >> 3) * CHUNK;
    #pragma unroll
    for (int i = 0; i < CHUNK / 256; ++i) {
        int j = base + threadIdx.x + i * 256;
        if (j < e) {
            int d = ei[e + j];
            if (__umulhi((unsigned)d, clsmag) == cls) {
                atomicAdd(&cnt[d], 1);
                atomicAdd(&degf[d], ew[j]);
            }
        }
    }
}

__global__ void dinv_kernel(const float* __restrict__ degf, float* __restrict__ dinv, int n) {
    int i = blockIdx.x * blockDim.x + threadIdx.x;
    if (i < n) dinv[i] = rsqrtf(degf[i]);   // degf >= 1 always (self-loop)
}

// ---- 3-kernel parallel scan: cnt[0..n) -> rowptr[n+1], cursor[n] ----------

__global__ __launch_bounds__(256) void scanA_kernel(const int* __restrict__ cnt,
                                                    int* __restrict__ bsum, int n) {
    __shared__ int wsum[4];
    int i = blockIdx.x * 256 + threadIdx.x;
    int v = (i < n) ? cnt[i] : 0;
    const int lane = threadIdx.x & 63, wid = threadIdx.x >> 6;
    #pragma unroll
    for (int d = 1; d < 64; d <<= 1) {
        int t = __shfl_up(v, d, 64);
        if (lane >= d) v += t;
    }
    if (lane == 63) wsum[wid] = v;
    __syncthreads();
    if (threadIdx.x == 0) bsum[blockIdx.x] = wsum[0] + wsum[1] + wsum[2] + wsum[3];
}

__global__ __launch_bounds__(256) void scanB_kernel(int* __restrict__ bsum, int nb) {
    __shared__ int wsum[4];
    const int tid = threadIdx.x, lane = tid & 63, wid = tid >> 6;
    int v = (tid < nb) ? bsum[tid] : 0;
    int incl = v;
    #pragma unroll
    for (int d = 1; d < 64; d <<= 1) {
        int t = __shfl_up(incl, d, 64);
        if (lane >= d) incl += t;
    }
    if (lane == 63) wsum[wid] = incl;
    __syncthreads();
    int woff = 0;
    for (int w = 0; w < wid; ++w) woff += wsum[w];
    if (tid < nb) bsum[tid] = woff + incl - v;   // exclusive
}

__global__ __launch_bounds__(256) void scanC_kernel(const int* __restrict__ cnt,
                                                    const int* __restrict__ bsum,
                                                    int* __restrict__ rowptr,
                                                    int* __restrict__ cursor, int n) {
    __shared__ int wsum[4];
    int i = blockIdx.x * 256 + threadIdx.x;
    int v = (i < n) ? cnt[i] : 0;
    const int lane = threadIdx.x & 63, wid = threadIdx.x >> 6;
    int incl = v;
    #pragma unroll
    for (int d = 1; d < 64; d <<= 1) {
        int t = __shfl_up(incl, d, 64);
        if (lane >= d) incl += t;
    }
    if (lane == 63) wsum[wid] = incl;
    __syncthreads();
    int woff = bsum[blockIdx.x];
    for (int w = 0; w < wid; ++w) woff += wsum[w];
    if (i < n) {
        int excl = woff + incl - v;
        cursor[i] = excl;
        rowptr[i + 1] = excl + v;
    }
    if (i == 0) rowptr[0] = 0;
}

// ---- class-filtered scatter of fully-normalized edges into CSR ------------

__global__ __launch_bounds__(256) void fill_kernel(const int* __restrict__ ei,
                                                   const float* __restrict__ ew,
                                                   const float* __restrict__ dinv,
                                                   int* __restrict__ cursor,
                                                   float2* __restrict__ pairs,
                                                   int e, int n, unsigned clsmag) {
    const unsigned cls = blockIdx.x & 7;
    const int base = (blockIdx.x >> 3) * CHUNK;
    #pragma unroll
    for (int i = 0; i < CHUNK / 256; ++i) {
        int j = base + threadIdx.x + i * 256;
        if (j < e) {
            int d = ei[e + j];
            if (__umulhi((unsigned)d, clsmag) == cls) {
                int s = ei[j];
                float nv = dinv[s] * ew[j] * dinv[d];
                int pos = atomicAdd(&cursor[d], 1);
                pairs[pos] = make_float2(__int_as_float(s), nv);
            }
        } else if (j < e + n) {
            int i2 = j - e;
            if (__umulhi((unsigned)i2, clsmag) == cls) {
                float dv = dinv[i2];
                int pos = atomicAdd(&cursor[i2], 1);
                pairs[pos] = make_float2(__int_as_float(i2), dv * dv);
            }
        }
    }
}

// ---------------------------------------------------------------------------
// GEMM: O[n][128] = X[n][K] @ W[K][128]   (SPLIT: W = [Wa(Kx64) | Wb(Kx64)])
// ---------------------------------------------------------------------------

template <int K, bool SPLIT>
__global__ __launch_bounds__(256) void gemm128_kernel(const float* __restrict__ X,
                                                      const float* __restrict__ Wa,
                                                      const float* __restrict__ Wb,
                                                      float* __restrict__ O, int n) {
    __shared__ float xs[64][33];
    __shared__ float ws[32][128];
    const int tid = threadIdx.x;
    const int rt = tid >> 5;   // 0..7
    const int ct = tid & 31;   // 0..31
    const int row0 = blockIdx.x * 64;

    float acc[8][4];
    #pragma unroll
    for (int r = 0; r < 8; ++r)
        #pragma unroll
        for (int j = 0; j < 4; ++j) acc[r][j] = 0.f;

    for (int k0 = 0; k0 < K; k0 += 32) {
        #pragma unroll
        for (int i = 0; i < 8; ++i) {
            int idx = tid + i * 256;
            int r = idx >> 5, kk = idx & 31;
            int row = row0 + r;
            xs[r][kk] = (row < n) ? X[(size_t)row * K + k0 + kk] : 0.f;
        }
        #pragma unroll
        for (int i = 0; i < 16; ++i) {
            int idx = tid + i * 256;
            int kr = idx >> 7, c = idx & 127;
            float w;
            if (SPLIT)
                w = (c < 64) ? Wa[(k0 + kr) * 64 + c] : Wb[(k0 + kr) * 64 + (c - 64)];
            else
                w = Wa[(k0 + kr) * 128 + c];
            ws[kr][c] = w;
        }
        __syncthreads();
        #pragma unroll
        for (int kk = 0; kk < 32; ++kk) {
            float wv[4];
            #pragma unroll
            for (int j = 0; j < 4; ++j) wv[j] = ws[kk][ct + 32 * j];
            #pragma unroll
            for (int rr = 0; rr < 8; ++rr) {
                float xv = xs[rt * 8 + rr][kk];
                #pragma unroll
                for (int j = 0; j < 4; ++j) acc[rr][j] += xv * wv[j];
            }
        }
        __syncthreads();
    }
    #pragma unroll
    for (int rr = 0; rr < 8; ++rr) {
        int row = row0 + rt * 8 + rr;
        if (row < n) {
            #pragma unroll
            for (int j = 0; j < 4; ++j) O[(size_t)row * 128 + ct + 32 * j] = acc[rr][j];
        }
    }
}

// ---------------------------------------------------------------------------
// Aggregation: one wave per node, float2 per lane (128 cols).
// pairs hold fully-normalized values -> out_row = sum + bias (no row scale).
// ---------------------------------------------------------------------------

__global__ __launch_bounds__(256) void agg1_kernel(const int* __restrict__ rowptr,
                                                   const float2* __restrict__ pairs,
                                                   const float* __restrict__ h0,
                                                   const float* __restrict__ b1,
                                                   float* __restrict__ h, int n) {
    const int lane = threadIdx.x & 63;
    const int node = blockIdx.x * 4 + (threadIdx.x >> 6);
    if (node >= n) return;
    const int start = rowptr[node];
    const int end = rowptr[node + 1];
    float2 acc = *(const float2*)&b1[2 * lane];
    int j = start;
    for (; j + 1 < end; j += 2) {
        float2 p0 = pairs[j], p1 = pairs[j + 1];
        int s0 = __float_as_int(p0.x), s1 = __float_as_int(p1.x);
        float2 a = *(const float2*)&h0[(size_t)s0 * 128 + 2 * lane];
        float2 b = *(const float2*)&h0[(size_t)s1 * 128 + 2 * lane];
        acc.x += p0.y * a.x + p1.y * b.x;
        acc.y += p0.y * a.y + p1.y * b.y;
    }
    if (j < end) {
        float2 p0 = pairs[j];
        int s0 = __float_as_int(p0.x);
        float2 a = *(const float2*)&h0[(size_t)s0 * 128 + 2 * lane];
        acc.x += p0.y * a.x;
        acc.y += p0.y * a.y;
    }
    acc.x = acc.x > 0.f ? acc.x : expm1f(acc.x);
    acc.y = acc.y > 0.f ? acc.y : expm1f(acc.y);
    *(float2*)&h[(size_t)node * 128 + 2 * lane] = acc;
}

__global__ __launch_bounds__(256) void agg2_kernel(const int* __restrict__ rowptr,
                                                   const float2* __restrict__ pairs,
                                                   const float* __restrict__ hcat,
                                                   const float* __restrict__ bmu,
                                                   const float* __restrict__ bls,
                                                   float* __restrict__ out, int n) {
    const int lane = threadIdx.x & 63;
    const int node = blockIdx.x * 4 + (threadIdx.x >> 6);
    if (node >= n) return;
    const int start = rowptr[node];
    const int end = rowptr[node + 1];
    const int ci = 2 * lane;  // 0..126
    float2 acc = make_float2(0.f, 0.f);
    int j = start;
    for (; j + 1 < end; j += 2) {
        float2 p0 = pairs[j], p1 = pairs[j + 1];
        int s0 = __float_as_int(p0.x), s1 = __float_as_int(p1.x);
        float2 a = *(const float2*)&hcat[(size_t)s0 * 128 + ci];
        float2 b = *(const float2*)&hcat[(size_t)s1 * 128 + ci];
        acc.x += p0.y * a.x + p1.y * b.x;
        acc.y += p0.y * a.y + p1.y * b.y;
    }
    if (j < end) {
        float2 p0 = pairs[j];
        int s0 = __float_as_int(p0.x);
        float2 a = *(const float2*)&hcat[(size_t)s0 * 128 + ci];
        acc.x += p0.y * a.x;
        acc.y += p0.y * a.y;
    }
    if (lane < 32) {
        acc.x += bmu[ci];
        acc.y += bmu[ci + 1];
        *(float2*)&out[(size_t)node * 64 + ci] = acc;
    } else {
        acc.x += bls[ci - 64];
        acc.y += bls[ci - 63];
        *(float2*)&out[(size_t)n * 64 + (size_t)node * 64 + (ci - 64)] = acc;
    }
}

// ---------------------------------------------------------------------------

extern "C" void kernel_launch(void* const* d_in, const int* in_sizes, int n_in,
                              void* d_out, int out_size, void* d_ws, size_t ws_size,
                              hipStream_t stream) {
    const float* x   = (const float*)d_in[0];
    const int*   ei  = (const int*)d_in[1];
    const float* ew  = (const float*)d_in[2];
    const float* W1  = (const float*)d_in[3];
    const float* b1  = (const float*)d_in[4];
    const float* Wmu = (const float*)d_in[5];
    const float* bmu = (const float*)d_in[6];
    const float* Wls = (const float*)d_in[7];
    const float* bls = (const float*)d_in[8];
    float*       out = (float*)d_out;

    const int n = in_sizes[0] / IN_C;     // 50000
    const int e = in_sizes[2];            // 1600000
    const int nnz = e + n;
    // class magic: cls(d) = umulhi(d, clsmag) == floor(d*8/n), monotone, <8
    const unsigned clsmag = (unsigned)((8ull << 32) / (unsigned)n + 1);

    char* ws = (char*)d_ws;
    size_t off = 0;
    auto alloc = [&](size_t bytes) -> void* {
        void* p = ws + off;
        off = (off + bytes + 255) & ~(size_t)255;
        return p;
    };
    int*    cnt    = (int*)   alloc((size_t)n * 4);
    float*  degf   = (float*) alloc((size_t)n * 4);
    int*    rowptr = (int*)   alloc((size_t)(n + 1) * 4);
    int*    cursor = (int*)   alloc((size_t)n * 4);
    int*    bsum   = (int*)   alloc(1024 * 4);
    float*  dinv   = (float*) alloc((size_t)n * 4);
    float2* pairs  = (float2*)alloc((size_t)nnz * 8);
    float*  bufA   = (float*) alloc((size_t)n * 128 * 4);  // h0, later hcat
    (void)ws_size;
    float* hbuf = out;   // layer-1 activations live in d_out, overwritten at end

    const int B = 256;
    const int nb = (n + 255) / 256;
    const int chunks_c = (e + CHUNK - 1) / CHUNK;
    const int chunks_f = (nnz + CHUNK - 1) / CHUNK;

    init_kernel<<<(n + B - 1) / B, B, 0, stream>>>(cnt, degf, n);
    countdeg_kernel<<<chunks_c * 8, 256, 0, stream>>>(ei, ew, cnt, degf, e, clsmag);
    dinv_kernel<<<(n + B - 1) / B, B, 0, stream>>>(degf, dinv, n);
    scanA_kernel<<<nb, 256, 0, stream>>>(cnt, bsum, n);
    scanB_kernel<<<1, 256, 0, stream>>>(bsum, nb);
    scanC_kernel<<<nb, 256, 0, stream>>>(cnt, bsum, rowptr, cursor, n);
    fill_kernel<<<chunks_f * 8, 256, 0, stream>>>(ei, ew, dinv, cursor, pairs, e, n, clsmag);

    gemm128_kernel<IN_C, false><<<(n + 63) / 64, 256, 0, stream>>>(x, W1, nullptr, bufA, n);
    agg1_kernel<<<(n + 3) / 4, 256, 0, stream>>>(rowptr, pairs, bufA, b1, hbuf, n);
    gemm128_kernel<HID, true><<<(n + 63) / 64, 256, 0, stream>>>(hbuf, Wmu, Wls, bufA, n);
    agg2_kernel<<<(n + 3) / 4, 256, 0, stream>>>(rowptr, pairs, bufA, bmu, bls, out, n);
}

// Round 5
// 486.214 us; speedup vs baseline: 1.3442x; 1.3442x over previous
//
#include <hip/hip_runtime.h>
#include <stdint.h>
#include <math.h>

#define IN_C 256
#define HID 128
#define OUT_C 64
#define NB 256        // dst buckets (== blockDim of bucket kernels)
#define CHUNK 4096    // edges per chunk in hist/scatter phases

// bucket(d) = umulhi(d, bmag) == floor(d*NB/n)  (monotone, contiguous ranges)

// ---------------------------------------------------------------------------
// Phase A: per-chunk histogram over dst buckets (LDS atomics only)
// ---------------------------------------------------------------------------
__global__ __launch_bounds__(256) void histA_kernel(const int* __restrict__ ei,
                                                    int* __restrict__ hist,
                                                    int e, int n, unsigned bmag) {
    __shared__ int h[NB];
    const int t = threadIdx.x;
    h[t] = 0;
    __syncthreads();
    const int base = blockIdx.x * CHUNK;
    #pragma unroll
    for (int i = 0; i < CHUNK / 256; ++i) {
        int j = base + t + i * 256;
        int d = -1;
        if (j < e) d = ei[e + j];
        else if (j < e + n) d = j - e;          // self-loop
        if (d >= 0) atomicAdd(&h[__umulhi((unsigned)d, bmag)], 1);
    }
    __syncthreads();
    hist[blockIdx.x * NB + t] = h[t];
}

// ---------------------------------------------------------------------------
// Phase B1: per-bucket exclusive scan over chunks (in place), totals out
// ---------------------------------------------------------------------------
__global__ __launch_bounds__(256) void scanB1_kernel(int* __restrict__ hist,
                                                     int* __restrict__ totals,
                                                     int nchunks) {
    __shared__ int buf[256];
    const int b = blockIdx.x;       // bucket
    const int t = threadIdx.x;
    int running = 0;
    for (int base = 0; base < nchunks; base += 256) {
        int idx = base + t;
        int v = (idx < nchunks) ? hist[idx * NB + b] : 0;
        buf[t] = v;
        __syncthreads();
        for (int g = 1; g < 256; g <<= 1) {
            int add = (t >= g) ? buf[t - g] : 0;
            __syncthreads();
            buf[t] += add;
            __syncthreads();
        }
        if (idx < nchunks) hist[idx * NB + b] = running + buf[t] - v;  // exclusive
        running += buf[255];
        __syncthreads();
    }
    if (t == 0) totals[b] = running;
}

// ---------------------------------------------------------------------------
// Phase B2: exclusive scan of bucket totals -> bbase[NB+1]
// ---------------------------------------------------------------------------
__global__ __launch_bounds__(256) void scanB2_kernel(const int* __restrict__ totals,
                                                     int* __restrict__ bbase) {
    __shared__ int buf[256];
    const int t = threadIdx.x;
    int v = totals[t];
    buf[t] = v;
    __syncthreads();
    for (int g = 1; g < 256; g <<= 1) {
        int add = (t >= g) ? buf[t - g] : 0;
        __syncthreads();
        buf[t] += add;
        __syncthreads();
    }
    bbase[t] = buf[t] - v;
    if (t == 255) bbase[256] = buf[255];
}

// ---------------------------------------------------------------------------
// Phase C: scatter edges to bucket-grouped temp arrays (LDS cursors, no
// global atomics). Writes are short runs local to the issuing XCD.
// ---------------------------------------------------------------------------
__global__ __launch_bounds__(256) void scatterC_kernel(const int* __restrict__ ei,
                                                       const float* __restrict__ ew,
                                                       const int* __restrict__ hist,
                                                       const int* __restrict__ bbase,
                                                       float2* __restrict__ ptmp,
                                                       int* __restrict__ dtmp,
                                                       int e, int n, unsigned bmag) {
    __shared__ int cur[NB];
    const int t = threadIdx.x;
    cur[t] = bbase[t] + hist[blockIdx.x * NB + t];
    __syncthreads();
    const int base = blockIdx.x * CHUNK;
    #pragma unroll
    for (int i = 0; i < CHUNK / 256; ++i) {
        int j = base + t + i * 256;
        if (j < e) {
            int d = ei[e + j];
            int s = ei[j];
            float w = ew[j];
            int pos = atomicAdd(&cur[__umulhi((unsigned)d, bmag)], 1);
            ptmp[pos] = make_float2(__int_as_float(s), w);
            dtmp[pos] = d;
        } else if (j < e + n) {
            int d = j - e;
            int pos = atomicAdd(&cur[__umulhi((unsigned)d, bmag)], 1);
            ptmp[pos] = make_float2(__int_as_float(d), 1.0f);
            dtmp[pos] = d;
        }
    }
}

// ---------------------------------------------------------------------------
// Phase D: one block per bucket. Count + weighted degree per node in LDS,
// block scan -> rowptr/dinv; re-scatter segment into final dst-sorted CSR
// with dinv[dst] folded into val. No global atomics.
// Assumes ceil(n/NB) <= 224 nodes per bucket (n=50000, NB=256 -> 196).
// ---------------------------------------------------------------------------
__global__ __launch_bounds__(256) void bucketD_kernel(const float2* __restrict__ ptmp,
                                                      const int* __restrict__ dtmp,
                                                      const int* __restrict__ bbase,
                                                      float2* __restrict__ pairs,
                                                      int* __restrict__ rowptr,
                                                      float* __restrict__ dinv,
                                                      int n, int nnz) {
    const int b = blockIdx.x;
    const int t = threadIdx.x;
    const int lo = (b * n + NB - 1) / NB;
    const int hi = ((b + 1) * n + NB - 1) / NB;
    const int nn = hi - lo;                       // <= 224
    __shared__ int   cnt[224];
    __shared__ float deg[224];
    __shared__ float dv[224];
    __shared__ int   cur2[224];
    __shared__ int   sb[256];
    if (t < nn) { cnt[t] = 0; deg[t] = 0.f; }
    __syncthreads();
    const int s0 = bbase[b], s1 = bbase[b + 1];
    for (int k = s0 + t; k < s1; k += 256) {
        int dl = dtmp[k] - lo;
        atomicAdd(&cnt[dl], 1);
        atomicAdd(&deg[dl], ptmp[k].y);
    }
    __syncthreads();
    int v = (t < nn) ? cnt[t] : 0;
    sb[t] = v;
    __syncthreads();
    for (int g = 1; g < 256; g <<= 1) {
        int add = (t >= g) ? sb[t - g] : 0;
        __syncthreads();
        sb[t] += add;
        __syncthreads();
    }
    if (t < nn) {
        int excl = sb[t] - v;
        int node = lo + t;
        float di = rsqrtf(deg[t]);                // deg >= 1 (self-loop)
        rowptr[node] = s0 + excl;
        dinv[node] = di;
        dv[t] = di;
        cur2[t] = s0 + excl;
    }
    __syncthreads();
    for (int k = s0 + t; k < s1; k += 256) {
        int dl = dtmp[k] - lo;
        float2 p = ptmp[k];
        int pos = atomicAdd(&cur2[dl], 1);
        pairs[pos] = make_float2(p.x, p.y * dv[dl]);
    }
    if (b == NB - 1 && t == 0) rowptr[n] = nnz;
}

// ---- val[k] *= dinv[col[k]]  (completes symmetric normalization) ----------
__global__ void fixup_kernel(float2* __restrict__ pairs, const float* __restrict__ dinv,
                             int nnz) {
    int k = blockIdx.x * blockDim.x + threadIdx.x;
    if (k < nnz) {
        float2 p = pairs[k];
        p.y *= dinv[__float_as_int(p.x)];
        pairs[k] = p;
    }
}

// ---------------------------------------------------------------------------
// GEMM: O[n][128] = X[n][K] @ W[K][128]   (SPLIT: W = [Wa(Kx64) | Wb(Kx64)])
// ---------------------------------------------------------------------------
template <int K, bool SPLIT>
__global__ __launch_bounds__(256) void gemm128_kernel(const float* __restrict__ X,
                                                      const float* __restrict__ Wa,
                                                      const float* __restrict__ Wb,
                                                      float* __restrict__ O, int n) {
    __shared__ float xs[64][33];
    __shared__ float ws[32][128];
    const int tid = threadIdx.x;
    const int rt = tid >> 5;   // 0..7
    const int ct = tid & 31;   // 0..31
    const int row0 = blockIdx.x * 64;

    float acc[8][4];
    #pragma unroll
    for (int r = 0; r < 8; ++r)
        #pragma unroll
        for (int j = 0; j < 4; ++j) acc[r][j] = 0.f;

    for (int k0 = 0; k0 < K; k0 += 32) {
        #pragma unroll
        for (int i = 0; i < 8; ++i) {
            int idx = tid + i * 256;
            int r = idx >> 5, kk = idx & 31;
            int row = row0 + r;
            xs[r][kk] = (row < n) ? X[(size_t)row * K + k0 + kk] : 0.f;
        }
        #pragma unroll
        for (int i = 0; i < 16; ++i) {
            int idx = tid + i * 256;
            int kr = idx >> 7, c = idx & 127;
            float w;
            if (SPLIT)
                w = (c < 64) ? Wa[(k0 + kr) * 64 + c] : Wb[(k0 + kr) * 64 + (c - 64)];
            else
                w = Wa[(k0 + kr) * 128 + c];
            ws[kr][c] = w;
        }
        __syncthreads();
        #pragma unroll
        for (int kk = 0; kk < 32; ++kk) {
            float wv[4];
            #pragma unroll
            for (int j = 0; j < 4; ++j) wv[j] = ws[kk][ct + 32 * j];
            #pragma unroll
            for (int rr = 0; rr < 8; ++rr) {
                float xv = xs[rt * 8 + rr][kk];
                #pragma unroll
                for (int j = 0; j < 4; ++j) acc[rr][j] += xv * wv[j];
            }
        }
        __syncthreads();
    }
    #pragma unroll
    for (int rr = 0; rr < 8; ++rr) {
        int row = row0 + rt * 8 + rr;
        if (row < n) {
            #pragma unroll
            for (int j = 0; j < 4; ++j) O[(size_t)row * 128 + ct + 32 * j] = acc[rr][j];
        }
    }
}

// ---------------------------------------------------------------------------
// Aggregation: one wave per node, float2 per lane. pairs fully normalized.
// ---------------------------------------------------------------------------
__global__ __launch_bounds__(256) void agg1_kernel(const int* __restrict__ rowptr,
                                                   const float2* __restrict__ pairs,
                                                   const float* __restrict__ h0,
                                                   const float* __restrict__ b1,
                                                   float* __restrict__ h, int n) {
    const int lane = threadIdx.x & 63;
    const int node = blockIdx.x * 4 + (threadIdx.x >> 6);
    if (node >= n) return;
    const int start = rowptr[node];
    const int end = rowptr[node + 1];
    float2 acc = *(const float2*)&b1[2 * lane];
    int j = start;
    for (; j + 1 < end; j += 2) {
        float2 p0 = pairs[j], p1 = pairs[j + 1];
        int s0 = __float_as_int(p0.x), s1 = __float_as_int(p1.x);
        float2 a = *(const float2*)&h0[(size_t)s0 * 128 + 2 * lane];
        float2 b = *(const float2*)&h0[(size_t)s1 * 128 + 2 * lane];
        acc.x += p0.y * a.x + p1.y * b.x;
        acc.y += p0.y * a.y + p1.y * b.y;
    }
    if (j < end) {
        float2 p0 = pairs[j];
        int s0 = __float_as_int(p0.x);
        float2 a = *(const float2*)&h0[(size_t)s0 * 128 + 2 * lane];
        acc.x += p0.y * a.x;
        acc.y += p0.y * a.y;
    }
    acc.x = acc.x > 0.f ? acc.x : expm1f(acc.x);
    acc.y = acc.y > 0.f ? acc.y : expm1f(acc.y);
    *(float2*)&h[(size_t)node * 128 + 2 * lane] = acc;
}

__global__ __launch_bounds__(256) void agg2_kernel(const int* __restrict__ rowptr,
                                                   const float2* __restrict__ pairs,
                                                   const float* __restrict__ hcat,
                                                   const float* __restrict__ bmu,
                                                   const float* __restrict__ bls,
                                                   float* __restrict__ out, int n) {
    const int lane = threadIdx.x & 63;
    const int node = blockIdx.x * 4 + (threadIdx.x >> 6);
    if (node >= n) return;
    const int start = rowptr[node];
    const int end = rowptr[node + 1];
    const int ci = 2 * lane;  // 0..126
    float2 acc = make_float2(0.f, 0.f);
    int j = start;
    for (; j + 1 < end; j += 2) {
        float2 p0 = pairs[j], p1 = pairs[j + 1];
        int s0 = __float_as_int(p0.x), s1 = __float_as_int(p1.x);
        float2 a = *(const float2*)&hcat[(size_t)s0 * 128 + ci];
        float2 b = *(const float2*)&hcat[(size_t)s1 * 128 + ci];
        acc.x += p0.y * a.x + p1.y * b.x;
        acc.y += p0.y * a.y + p1.y * b.y;
    }
    if (j < end) {
        float2 p0 = pairs[j];
        int s0 = __float_as_int(p0.x);
        float2 a = *(const float2*)&hcat[(size_t)s0 * 128 + ci];
        acc.x += p0.y * a.x;
        acc.y += p0.y * a.y;
    }
    if (lane < 32) {
        acc.x += bmu[ci];
        acc.y += bmu[ci + 1];
        *(float2*)&out[(size_t)node * 64 + ci] = acc;
    } else {
        acc.x += bls[ci - 64];
        acc.y += bls[ci - 63];
        *(float2*)&out[(size_t)n * 64 + (size_t)node * 64 + (ci - 64)] = acc;
    }
}

// ---------------------------------------------------------------------------

extern "C" void kernel_launch(void* const* d_in, const int* in_sizes, int n_in,
                              void* d_out, int out_size, void* d_ws, size_t ws_size,
                              hipStream_t stream) {
    const float* x   = (const float*)d_in[0];
    const int*   ei  = (const int*)d_in[1];
    const float* ew  = (const float*)d_in[2];
    const float* W1  = (const float*)d_in[3];
    const float* b1  = (const float*)d_in[4];
    const float* Wmu = (const float*)d_in[5];
    const float* bmu = (const float*)d_in[6];
    const float* Wls = (const float*)d_in[7];
    const float* bls = (const float*)d_in[8];
    float*       out = (float*)d_out;

    const int n = in_sizes[0] / IN_C;     // 50000
    const int e = in_sizes[2];            // 1600000
    const int nnz = e + n;
    const int nchunks = (nnz + CHUNK - 1) / CHUNK;
    const unsigned bmag = (unsigned)(((unsigned long long)NB << 32) / (unsigned)n + 1);

    char* ws = (char*)d_ws;
    size_t off = 0;
    auto alloc = [&](size_t bytes) -> void* {
        void* p = ws + off;
        off = (off + bytes + 255) & ~(size_t)255;
        return p;
    };
    // persistent
    int*    hist   = (int*)   alloc((size_t)nchunks * NB * 4);
    int*    totals = (int*)   alloc(NB * 4);
    int*    bbase  = (int*)   alloc((NB + 1) * 4);
    int*    rowptr = (int*)   alloc((size_t)(n + 1) * 4);
    float*  dinv   = (float*) alloc((size_t)n * 4);
    float2* pairs  = (float2*)alloc((size_t)nnz * 8);
    // overlapped region: {ptmp+dtmp} before GEMMs, bufA after
    char*   shared_base = (char*)alloc((size_t)n * 128 * 4);   // 25.6 MB >= 19.8 MB
    float2* ptmp = (float2*)shared_base;
    int*    dtmp = (int*)(shared_base + (size_t)nnz * 8);
    float*  bufA = (float*)shared_base;
    (void)ws_size;
    float* hbuf = out;   // layer-1 activations live in d_out, overwritten at end

    histA_kernel<<<nchunks, 256, 0, stream>>>(ei, hist, e, n, bmag);
    scanB1_kernel<<<NB, 256, 0, stream>>>(hist, totals, nchunks);
    scanB2_kernel<<<1, 256, 0, stream>>>(totals, bbase);
    scatterC_kernel<<<nchunks, 256, 0, stream>>>(ei, ew, hist, bbase, ptmp, dtmp, e, n, bmag);
    bucketD_kernel<<<NB, 256, 0, stream>>>(ptmp, dtmp, bbase, pairs, rowptr, dinv, n, nnz);
    fixup_kernel<<<(nnz + 255) / 256, 256, 0, stream>>>(pairs, dinv, nnz);

    gemm128_kernel<IN_C, false><<<(n + 63) / 64, 256, 0, stream>>>(x, W1, nullptr, bufA, n);
    agg1_kernel<<<(n + 3) / 4, 256, 0, stream>>>(rowptr, pairs, bufA, b1, hbuf, n);
    gemm128_kernel<HID, true><<<(n + 63) / 64, 256, 0, stream>>>(hbuf, Wmu, Wls, bufA, n);
    agg2_kernel<<<(n + 3) / 4, 256, 0, stream>>>(rowptr, pairs, bufA, bmu, bls, out, n);
}

// Round 6
// 376.308 us; speedup vs baseline: 1.7367x; 1.2921x over previous
//
#include <hip/hip_runtime.h>
#include <stdint.h>
#include <math.h>

#define IN_C 256
#define HID 128
#define OUT_C 64
#define NB 256        // dst buckets
#define CHUNK 4096    // edges per chunk in hist/scatter phases

typedef __attribute__((ext_vector_type(8))) short bf16x8;
typedef __attribute__((ext_vector_type(4))) float f32x4;

__device__ inline ushort f2bf(float f) {
    uint u = __float_as_uint(f);
    u += 0x7fff + ((u >> 16) & 1);           // RNE
    return (ushort)(u >> 16);
}
__device__ inline void split2(float f, ushort& h, ushort& l) {
    h = f2bf(f);
    float fh = __uint_as_float(((uint)h) << 16);
    l = f2bf(f - fh);
}

// ---------------------------------------------------------------------------
// Preprocessing (unchanged from round 5): bucket-sort CSR build, no global
// atomics. bucket(d) = umulhi(d, bmag) = floor(d*NB/n).
// ---------------------------------------------------------------------------
__global__ __launch_bounds__(256) void histA_kernel(const int* __restrict__ ei,
                                                    int* __restrict__ hist,
                                                    int e, int n, unsigned bmag) {
    __shared__ int h[NB];
    const int t = threadIdx.x;
    h[t] = 0;
    __syncthreads();
    const int base = blockIdx.x * CHUNK;
    #pragma unroll
    for (int i = 0; i < CHUNK / 256; ++i) {
        int j = base + t + i * 256;
        int d = -1;
        if (j < e) d = ei[e + j];
        else if (j < e + n) d = j - e;          // self-loop
        if (d >= 0) atomicAdd(&h[__umulhi((unsigned)d, bmag)], 1);
    }
    __syncthreads();
    hist[blockIdx.x * NB + t] = h[t];
}

__global__ __launch_bounds__(256) void scanB1_kernel(int* __restrict__ hist,
                                                     int* __restrict__ totals,
                                                     int nchunks) {
    __shared__ int buf[256];
    const int b = blockIdx.x;
    const int t = threadIdx.x;
    int running = 0;
    for (int base = 0; base < nchunks; base += 256) {
        int idx = base + t;
        int v = (idx < nchunks) ? hist[idx * NB + b] : 0;
        buf[t] = v;
        __syncthreads();
        for (int g = 1; g < 256; g <<= 1) {
            int add = (t >= g) ? buf[t - g] : 0;
            __syncthreads();
            buf[t] += add;
            __syncthreads();
        }
        if (idx < nchunks) hist[idx * NB + b] = running + buf[t] - v;
        running += buf[255];
        __syncthreads();
    }
    if (t == 0) totals[b] = running;
}

__global__ __launch_bounds__(256) void scanB2_kernel(const int* __restrict__ totals,
                                                     int* __restrict__ bbase) {
    __shared__ int buf[256];
    const int t = threadIdx.x;
    int v = totals[t];
    buf[t] = v;
    __syncthreads();
    for (int g = 1; g < 256; g <<= 1) {
        int add = (t >= g) ? buf[t - g] : 0;
        __syncthreads();
        buf[t] += add;
        __syncthreads();
    }
    bbase[t] = buf[t] - v;
    if (t == 255) bbase[256] = buf[255];
}

__global__ __launch_bounds__(256) void scatterC_kernel(const int* __restrict__ ei,
                                                       const float* __restrict__ ew,
                                                       const int* __restrict__ hist,
                                                       const int* __restrict__ bbase,
                                                       float2* __restrict__ ptmp,
                                                       int* __restrict__ dtmp,
                                                       int e, int n, unsigned bmag) {
    __shared__ int cur[NB];
    const int t = threadIdx.x;
    cur[t] = bbase[t] + hist[blockIdx.x * NB + t];
    __syncthreads();
    const int base = blockIdx.x * CHUNK;
    #pragma unroll
    for (int i = 0; i < CHUNK / 256; ++i) {
        int j = base + t + i * 256;
        if (j < e) {
            int d = ei[e + j];
            int s = ei[j];
            float w = ew[j];
            int pos = atomicAdd(&cur[__umulhi((unsigned)d, bmag)], 1);
            ptmp[pos] = make_float2(__int_as_float(s), w);
            dtmp[pos] = d;
        } else if (j < e + n) {
            int d = j - e;
            int pos = atomicAdd(&cur[__umulhi((unsigned)d, bmag)], 1);
            ptmp[pos] = make_float2(__int_as_float(d), 1.0f);
            dtmp[pos] = d;
        }
    }
}

__global__ __launch_bounds__(256) void bucketD_kernel(const float2* __restrict__ ptmp,
                                                      const int* __restrict__ dtmp,
                                                      const int* __restrict__ bbase,
                                                      float2* __restrict__ pairs,
                                                      int* __restrict__ rowptr,
                                                      float* __restrict__ dinv,
                                                      int n, int nnz) {
    const int b = blockIdx.x;
    const int t = threadIdx.x;
    const int lo = (b * n + NB - 1) / NB;
    const int hi = ((b + 1) * n + NB - 1) / NB;
    const int nn = hi - lo;                       // <= 224
    __shared__ int   cnt[224];
    __shared__ float deg[224];
    __shared__ float dv[224];
    __shared__ int   cur2[224];
    __shared__ int   sb[256];
    if (t < nn) { cnt[t] = 0; deg[t] = 0.f; }
    __syncthreads();
    const int s0 = bbase[b], s1 = bbase[b + 1];
    for (int k = s0 + t; k < s1; k += 256) {
        int dl = dtmp[k] - lo;
        atomicAdd(&cnt[dl], 1);
        atomicAdd(&deg[dl], ptmp[k].y);
    }
    __syncthreads();
    int v = (t < nn) ? cnt[t] : 0;
    sb[t] = v;
    __syncthreads();
    for (int g = 1; g < 256; g <<= 1) {
        int add = (t >= g) ? sb[t - g] : 0;
        __syncthreads();
        sb[t] += add;
        __syncthreads();
    }
    if (t < nn) {
        int excl = sb[t] - v;
        int node = lo + t;
        float di = rsqrtf(deg[t]);
        rowptr[node] = s0 + excl;
        dinv[node] = di;
        dv[t] = di;
        cur2[t] = s0 + excl;
    }
    __syncthreads();
    for (int k = s0 + t; k < s1; k += 256) {
        int dl = dtmp[k] - lo;
        float2 p = ptmp[k];
        int pos = atomicAdd(&cur2[dl], 1);
        pairs[pos] = make_float2(p.x, p.y * dv[dl]);
    }
    if (b == NB - 1 && t == 0) rowptr[n] = nnz;
}

__global__ void fixup_kernel(float2* __restrict__ pairs, const float* __restrict__ dinv,
                             int nnz) {
    int k = blockIdx.x * blockDim.x + threadIdx.x;
    if (k < nnz) {
        float2 p = pairs[k];
        p.y *= dinv[__float_as_int(p.x)];
        pairs[k] = p;
    }
}

// ---------------------------------------------------------------------------
// Weight split: logical W[k][c] (c in [0,128)) -> wt_hi/wt_lo [c][Kdim] bf16
// (k-contiguous per col). splitcols: W = [Wa(Kx64) | Wb(Kx64)].
// ---------------------------------------------------------------------------
__global__ void wsplit_kernel(const float* __restrict__ Wa, const float* __restrict__ Wb,
                              ushort* __restrict__ hi, ushort* __restrict__ lo,
                              int Kdim, int splitcols) {
    int idx = blockIdx.x * blockDim.x + threadIdx.x;
    if (idx >= Kdim * 128) return;
    int k = idx >> 7, c = idx & 127;
    float w = splitcols ? ((c < 64) ? Wa[k * 64 + c] : Wb[k * 64 + (c - 64)])
                        : Wa[k * 128 + c];
    ushort h, l;
    split2(w, h, l);
    hi[(size_t)c * Kdim + k] = h;
    lo[(size_t)c * Kdim + k] = l;
}

// ---------------------------------------------------------------------------
// MFMA GEMM: O[n][128](bf16) = X[n][K](f32) @ W[K][128], via bf16 hi/lo split
// (hi*hi + hi*lo + lo*hi; fp32 accumulate). Block: 256 thr / 4 waves,
// tile 64 rows x 128 cols; wave w owns rows 16w..16w+15, all 8 col-tiles.
// A-frag: row=l&15, k=8*(l>>4)+j (from LDS); B-frag identical mapping from
// wt[c][k] global (L2-hot). Same-kappa on A and B => correct for any kappa.
// D: col=l&15, row=4*(l>>4)+r (HW-verified).
// ---------------------------------------------------------------------------
template <int K>
__global__ __launch_bounds__(256) void gemm_mfma_kernel(const float* __restrict__ X,
                                                        const ushort* __restrict__ wt_hi,
                                                        const ushort* __restrict__ wt_lo,
                                                        ushort* __restrict__ O, int n) {
    __shared__ ushort xs_hi[64][40];   // 32 k + 8 pad -> 80 B rows (16B aligned)
    __shared__ ushort xs_lo[64][40];
    const int tid = threadIdx.x;
    const int wid = tid >> 6;
    const int lane = tid & 63;
    const int arow = lane & 15;
    const int kgrp = lane >> 4;
    const int row0 = blockIdx.x * 64;

    f32x4 acc[8];
    #pragma unroll
    for (int t = 0; t < 8; ++t) acc[t] = (f32x4){0.f, 0.f, 0.f, 0.f};

    for (int k0 = 0; k0 < K; k0 += 32) {
        #pragma unroll
        for (int i = 0; i < 2; ++i) {
            int idx = tid + i * 256;          // 512 float4 slots: 64 rows x 8
            int r = idx >> 3;
            int kq = (idx & 7) * 4;
            int row = row0 + r;
            float4 v = (row < n) ? *(const float4*)&X[(size_t)row * K + k0 + kq]
                                 : make_float4(0.f, 0.f, 0.f, 0.f);
            ushort4 h4, l4;
            split2(v.x, h4.x, l4.x);
            split2(v.y, h4.y, l4.y);
            split2(v.z, h4.z, l4.z);
            split2(v.w, h4.w, l4.w);
            *(ushort4*)&xs_hi[r][kq] = h4;
            *(ushort4*)&xs_lo[r][kq] = l4;
        }
        __syncthreads();
        bf16x8 a_hi = *(const bf16x8*)&xs_hi[wid * 16 + arow][kgrp * 8];
        bf16x8 a_lo = *(const bf16x8*)&xs_lo[wid * 16 + arow][kgrp * 8];
        #pragma unroll
        for (int ct = 0; ct < 8; ++ct) {
            const size_t wof = (size_t)(ct * 16 + arow) * K + k0 + kgrp * 8;
            bf16x8 b_hi = *(const bf16x8*)&wt_hi[wof];
            bf16x8 b_lo = *(const bf16x8*)&wt_lo[wof];
            acc[ct] = __builtin_amdgcn_mfma_f32_16x16x32_bf16(a_hi, b_hi, acc[ct], 0, 0, 0);
            acc[ct] = __builtin_amdgcn_mfma_f32_16x16x32_bf16(a_hi, b_lo, acc[ct], 0, 0, 0);
            acc[ct] = __builtin_amdgcn_mfma_f32_16x16x32_bf16(a_lo, b_hi, acc[ct], 0, 0, 0);
        }
        __syncthreads();
    }
    #pragma unroll
    for (int ct = 0; ct < 8; ++ct) {
        #pragma unroll
        for (int r = 0; r < 4; ++r) {
            int row = row0 + wid * 16 + kgrp * 4 + r;
            if (row < n) O[(size_t)row * 128 + ct * 16 + arow] = f2bf(acc[ct][r]);
        }
    }
}

// ---------------------------------------------------------------------------
// Aggregation over bf16 rows: one wave per node, 1 uint (2 bf16) per lane.
// ---------------------------------------------------------------------------
__global__ __launch_bounds__(256) void agg1_kernel(const int* __restrict__ rowptr,
                                                   const float2* __restrict__ pairs,
                                                   const uint* __restrict__ h0,  // [n][64] uints
                                                   const float* __restrict__ b1,
                                                   float* __restrict__ h, int n) {
    const int lane = threadIdx.x & 63;
    const int node = blockIdx.x * 4 + (threadIdx.x >> 6);
    if (node >= n) return;
    const int start = rowptr[node];
    const int end = rowptr[node + 1];
    float2 acc = *(const float2*)&b1[2 * lane];
    int j = start;
    for (; j + 1 < end; j += 2) {
        float2 p0 = pairs[j], p1 = pairs[j + 1];
        uint ua = h0[(size_t)__float_as_int(p0.x) * 64 + lane];
        uint ub = h0[(size_t)__float_as_int(p1.x) * 64 + lane];
        acc.x += p0.y * __uint_as_float(ua << 16) + p1.y * __uint_as_float(ub << 16);
        acc.y += p0.y * __uint_as_float(ua & 0xffff0000u) + p1.y * __uint_as_float(ub & 0xffff0000u);
    }
    if (j < end) {
        float2 p0 = pairs[j];
        uint ua = h0[(size_t)__float_as_int(p0.x) * 64 + lane];
        acc.x += p0.y * __uint_as_float(ua << 16);
        acc.y += p0.y * __uint_as_float(ua & 0xffff0000u);
    }
    acc.x = acc.x > 0.f ? acc.x : expm1f(acc.x);
    acc.y = acc.y > 0.f ? acc.y : expm1f(acc.y);
    *(float2*)&h[(size_t)node * 128 + 2 * lane] = acc;
}

__global__ __launch_bounds__(256) void agg2_kernel(const int* __restrict__ rowptr,
                                                   const float2* __restrict__ pairs,
                                                   const uint* __restrict__ hcat, // [n][64] uints
                                                   const float* __restrict__ bmu,
                                                   const float* __restrict__ bls,
                                                   float* __restrict__ out, int n) {
    const int lane = threadIdx.x & 63;
    const int node = blockIdx.x * 4 + (threadIdx.x >> 6);
    if (node >= n) return;
    const int start = rowptr[node];
    const int end = rowptr[node + 1];
    const int ci = 2 * lane;
    float2 acc = make_float2(0.f, 0.f);
    int j = start;
    for (; j + 1 < end; j += 2) {
        float2 p0 = pairs[j], p1 = pairs[j + 1];
        uint ua = hcat[(size_t)__float_as_int(p0.x) * 64 + lane];
        uint ub = hcat[(size_t)__float_as_int(p1.x) * 64 + lane];
        acc.x += p0.y * __uint_as_float(ua << 16) + p1.y * __uint_as_float(ub << 16);
        acc.y += p0.y * __uint_as_float(ua & 0xffff0000u) + p1.y * __uint_as_float(ub & 0xffff0000u);
    }
    if (j < end) {
        float2 p0 = pairs[j];
        uint ua = hcat[(size_t)__float_as_int(p0.x) * 64 + lane];
        acc.x += p0.y * __uint_as_float(ua << 16);
        acc.y += p0.y * __uint_as_float(ua & 0xffff0000u);
    }
    if (lane < 32) {
        acc.x += bmu[ci];
        acc.y += bmu[ci + 1];
        *(float2*)&out[(size_t)node * 64 + ci] = acc;
    } else {
        acc.x += bls[ci - 64];
        acc.y += bls[ci - 63];
        *(float2*)&out[(size_t)n * 64 + (size_t)node * 64 + (ci - 64)] = acc;
    }
}

// ---------------------------------------------------------------------------

extern "C" void kernel_launch(void* const* d_in, const int* in_sizes, int n_in,
                              void* d_out, int out_size, void* d_ws, size_t ws_size,
                              hipStream_t stream) {
    const float* x   = (const float*)d_in[0];
    const int*   ei  = (const int*)d_in[1];
    const float* ew  = (const float*)d_in[2];
    const float* W1  = (const float*)d_in[3];
    const float* b1  = (const float*)d_in[4];
    const float* Wmu = (const float*)d_in[5];
    const float* bmu = (const float*)d_in[6];
    const float* Wls = (const float*)d_in[7];
    const float* bls = (const float*)d_in[8];
    float*       out = (float*)d_out;

    const int n = in_sizes[0] / IN_C;     // 50000
    const int e = in_sizes[2];            // 1600000
    const int nnz = e + n;
    const int nchunks = (nnz + CHUNK - 1) / CHUNK;
    const unsigned bmag = (unsigned)(((unsigned long long)NB << 32) / (unsigned)n + 1);

    char* ws = (char*)d_ws;
    size_t off = 0;
    auto alloc = [&](size_t bytes) -> void* {
        void* p = ws + off;
        off = (off + bytes + 255) & ~(size_t)255;
        return p;
    };
    int*    hist   = (int*)   alloc((size_t)nchunks * NB * 4);
    int*    totals = (int*)   alloc(NB * 4);
    int*    bbase  = (int*)   alloc((NB + 1) * 4);
    int*    rowptr = (int*)   alloc((size_t)(n + 1) * 4);
    float*  dinv   = (float*) alloc((size_t)n * 4);
    float2* pairs  = (float2*)alloc((size_t)nnz * 8);
    ushort* wt1_hi = (ushort*)alloc((size_t)128 * IN_C * 2);
    ushort* wt1_lo = (ushort*)alloc((size_t)128 * IN_C * 2);
    ushort* wt2_hi = (ushort*)alloc((size_t)128 * HID * 2);
    ushort* wt2_lo = (ushort*)alloc((size_t)128 * HID * 2);
    // overlapped region: {ptmp+dtmp} during preprocessing; h0/hcat (bf16) after
    char*   shared_base = (char*)alloc((size_t)nnz * 12 + 1024);
    float2* ptmp = (float2*)shared_base;
    int*    dtmp = (int*)(shared_base + (size_t)nnz * 8);
    ushort* h0   = (ushort*)shared_base;        // [n][128] bf16 (12.8 MB)
    ushort* hcat = (ushort*)shared_base;        // reuses h0 (dead after agg1)
    (void)ws_size;
    float* hbuf = out;   // layer-1 activations (fp32) live in d_out

    histA_kernel<<<nchunks, 256, 0, stream>>>(ei, hist, e, n, bmag);
    scanB1_kernel<<<NB, 256, 0, stream>>>(hist, totals, nchunks);
    scanB2_kernel<<<1, 256, 0, stream>>>(totals, bbase);
    scatterC_kernel<<<nchunks, 256, 0, stream>>>(ei, ew, hist, bbase, ptmp, dtmp, e, n, bmag);
    bucketD_kernel<<<NB, 256, 0, stream>>>(ptmp, dtmp, bbase, pairs, rowptr, dinv, n, nnz);
    fixup_kernel<<<(nnz + 255) / 256, 256, 0, stream>>>(pairs, dinv, nnz);
    wsplit_kernel<<<(IN_C * 128 + 255) / 256, 256, 0, stream>>>(W1, nullptr, wt1_hi, wt1_lo, IN_C, 0);
    wsplit_kernel<<<(HID * 128 + 255) / 256, 256, 0, stream>>>(Wmu, Wls, wt2_hi, wt2_lo, HID, 1);

    gemm_mfma_kernel<IN_C><<<(n + 63) / 64, 256, 0, stream>>>(x, wt1_hi, wt1_lo, h0, n);
    agg1_kernel<<<(n + 3) / 4, 256, 0, stream>>>(rowptr, pairs, (const uint*)h0, b1, hbuf, n);
    gemm_mfma_kernel<HID><<<(n + 63) / 64, 256, 0, stream>>>(hbuf, wt2_hi, wt2_lo, hcat, n);
    agg2_kernel<<<(n + 3) / 4, 256, 0, stream>>>(rowptr, pairs, (const uint*)hcat, bmu, bls, out, n);
}

// Round 7
// 299.756 us; speedup vs baseline: 2.1803x; 1.2554x over previous
//
#include <hip/hip_runtime.h>
#include <stdint.h>
#include <math.h>

#define IN_C 256
#define HID 128
#define OUT_C 64
#define NB 256        // dst buckets
#define CHUNK 4096    // edges per chunk in hist/scatter phases

typedef __attribute__((ext_vector_type(8))) short bf16x8;
typedef __attribute__((ext_vector_type(4))) float f32x4;

__device__ inline ushort f2bf(float f) {
    uint u = __float_as_uint(f);
    u += 0x7fff + ((u >> 16) & 1);           // RNE
    return (ushort)(u >> 16);
}
__device__ inline void split2(float f, ushort& h, ushort& l) {
    h = f2bf(f);
    float fh = __uint_as_float(((uint)h) << 16);
    l = f2bf(f - fh);
}

// ---------------------------------------------------------------------------
// Preprocessing: bucket-sort CSR build, no global atomics.
// bucket(d) = umulhi(d, bmag) = floor(d*NB/n).
// ---------------------------------------------------------------------------
__global__ __launch_bounds__(256) void histA_kernel(const int* __restrict__ ei,
                                                    int* __restrict__ hist,
                                                    int e, int n, unsigned bmag) {
    __shared__ int h[NB];
    const int t = threadIdx.x;
    h[t] = 0;
    __syncthreads();
    const int base = blockIdx.x * CHUNK;
    #pragma unroll
    for (int i = 0; i < CHUNK / 256; ++i) {
        int j = base + t + i * 256;
        int d = -1;
        if (j < e) d = ei[e + j];
        else if (j < e + n) d = j - e;          // self-loop
        if (d >= 0) atomicAdd(&h[__umulhi((unsigned)d, bmag)], 1);
    }
    __syncthreads();
    hist[blockIdx.x * NB + t] = h[t];
}

__global__ __launch_bounds__(256) void scanB1_kernel(int* __restrict__ hist,
                                                     int* __restrict__ totals,
                                                     int nchunks) {
    __shared__ int buf[256];
    const int b = blockIdx.x;
    const int t = threadIdx.x;
    int running = 0;
    for (int base = 0; base < nchunks; base += 256) {
        int idx = base + t;
        int v = (idx < nchunks) ? hist[idx * NB + b] : 0;
        buf[t] = v;
        __syncthreads();
        for (int g = 1; g < 256; g <<= 1) {
            int add = (t >= g) ? buf[t - g] : 0;
            __syncthreads();
            buf[t] += add;
            __syncthreads();
        }
        if (idx < nchunks) hist[idx * NB + b] = running + buf[t] - v;
        running += buf[255];
        __syncthreads();
    }
    if (t == 0) totals[b] = running;
}

__global__ __launch_bounds__(256) void scanB2_kernel(const int* __restrict__ totals,
                                                     int* __restrict__ bbase) {
    __shared__ int buf[256];
    const int t = threadIdx.x;
    int v = totals[t];
    buf[t] = v;
    __syncthreads();
    for (int g = 1; g < 256; g <<= 1) {
        int add = (t >= g) ? buf[t - g] : 0;
        __syncthreads();
        buf[t] += add;
        __syncthreads();
    }
    bbase[t] = buf[t] - v;
    if (t == 255) bbase[256] = buf[255];
}

__global__ __launch_bounds__(256) void scatterC_kernel(const int* __restrict__ ei,
                                                       const float* __restrict__ ew,
                                                       const int* __restrict__ hist,
                                                       const int* __restrict__ bbase,
                                                       float2* __restrict__ ptmp,
                                                       int* __restrict__ dtmp,
                                                       int e, int n, unsigned bmag) {
    __shared__ int cur[NB];
    const int t = threadIdx.x;
    cur[t] = bbase[t] + hist[blockIdx.x * NB + t];
    __syncthreads();
    const int base = blockIdx.x * CHUNK;
    #pragma unroll
    for (int i = 0; i < CHUNK / 256; ++i) {
        int j = base + t + i * 256;
        if (j < e) {
            int d = ei[e + j];
            int s = ei[j];
            float w = ew[j];
            int pos = atomicAdd(&cur[__umulhi((unsigned)d, bmag)], 1);
            ptmp[pos] = make_float2(__int_as_float(s), w);
            dtmp[pos] = d;
        } else if (j < e + n) {
            int d = j - e;
            int pos = atomicAdd(&cur[__umulhi((unsigned)d, bmag)], 1);
            ptmp[pos] = make_float2(__int_as_float(d), 1.0f);
            dtmp[pos] = d;
        }
    }
}

__global__ __launch_bounds__(256) void bucketD_kernel(const float2* __restrict__ ptmp,
                                                      const int* __restrict__ dtmp,
                                                      const int* __restrict__ bbase,
                                                      float2* __restrict__ pairs,
                                                      int* __restrict__ rowptr,
                                                      float* __restrict__ dinv,
                                                      int n, int nnz) {
    const int b = blockIdx.x;
    const int t = threadIdx.x;
    const int lo = (b * n + NB - 1) / NB;
    const int hi = ((b + 1) * n + NB - 1) / NB;
    const int nn = hi - lo;                       // <= 224
    __shared__ int   cnt[224];
    __shared__ float deg[224];
    __shared__ float dv[224];
    __shared__ int   cur2[224];
    __shared__ int   sb[256];
    if (t < nn) { cnt[t] = 0; deg[t] = 0.f; }
    __syncthreads();
    const int s0 = bbase[b], s1 = bbase[b + 1];
    for (int k = s0 + t; k < s1; k += 256) {
        int dl = dtmp[k] - lo;
        atomicAdd(&cnt[dl], 1);
        atomicAdd(&deg[dl], ptmp[k].y);
    }
    __syncthreads();
    int v = (t < nn) ? cnt[t] : 0;
    sb[t] = v;
    __syncthreads();
    for (int g = 1; g < 256; g <<= 1) {
        int add = (t >= g) ? sb[t - g] : 0;
        __syncthreads();
        sb[t] += add;
        __syncthreads();
    }
    if (t < nn) {
        int excl = sb[t] - v;
        int node = lo + t;
        float di = rsqrtf(deg[t]);
        rowptr[node] = s0 + excl;
        dinv[node] = di;
        dv[t] = di;
        cur2[t] = s0 + excl;
    }
    __syncthreads();
    for (int k = s0 + t; k < s1; k += 256) {
        int dl = dtmp[k] - lo;
        float2 p = ptmp[k];
        int pos = atomicAdd(&cur2[dl], 1);
        pairs[pos] = make_float2(p.x, p.y * dv[dl]);
    }
    if (b == NB - 1 && t == 0) rowptr[n] = nnz;
}

__global__ void fixup_kernel(float2* __restrict__ pairs, const float* __restrict__ dinv,
                             int nnz) {
    int k = blockIdx.x * blockDim.x + threadIdx.x;
    if (k < nnz) {
        float2 p = pairs[k];
        p.y *= dinv[__float_as_int(p.x)];
        pairs[k] = p;
    }
}

// ---------------------------------------------------------------------------
// Weight split: logical W[k][c] (c in [0,128)) -> wt_hi/wt_lo [c][Kdim] bf16
// ---------------------------------------------------------------------------
__global__ void wsplit_kernel(const float* __restrict__ Wa, const float* __restrict__ Wb,
                              ushort* __restrict__ hi, ushort* __restrict__ lo,
                              int Kdim, int splitcols) {
    int idx = blockIdx.x * blockDim.x + threadIdx.x;
    if (idx >= Kdim * 128) return;
    int k = idx >> 7, c = idx & 127;
    float w = splitcols ? ((c < 64) ? Wa[k * 64 + c] : Wb[k * 64 + (c - 64)])
                        : Wa[k * 128 + c];
    ushort h, l;
    split2(w, h, l);
    hi[(size_t)c * Kdim + k] = h;
    lo[(size_t)c * Kdim + k] = l;
}

// ---------------------------------------------------------------------------
// MFMA GEMM: O[n][128](bf16) = X[n][K](f32) @ W[K][128], bf16 hi/lo split.
// ---------------------------------------------------------------------------
template <int K>
__global__ __launch_bounds__(256) void gemm_mfma_kernel(const float* __restrict__ X,
                                                        const ushort* __restrict__ wt_hi,
                                                        const ushort* __restrict__ wt_lo,
                                                        ushort* __restrict__ O, int n) {
    __shared__ ushort xs_hi[64][40];
    __shared__ ushort xs_lo[64][40];
    const int tid = threadIdx.x;
    const int wid = tid >> 6;
    const int lane = tid & 63;
    const int arow = lane & 15;
    const int kgrp = lane >> 4;
    const int row0 = blockIdx.x * 64;

    f32x4 acc[8];
    #pragma unroll
    for (int t = 0; t < 8; ++t) acc[t] = (f32x4){0.f, 0.f, 0.f, 0.f};

    for (int k0 = 0; k0 < K; k0 += 32) {
        #pragma unroll
        for (int i = 0; i < 2; ++i) {
            int idx = tid + i * 256;
            int r = idx >> 3;
            int kq = (idx & 7) * 4;
            int row = row0 + r;
            float4 v = (row < n) ? *(const float4*)&X[(size_t)row * K + k0 + kq]
                                 : make_float4(0.f, 0.f, 0.f, 0.f);
            ushort4 h4, l4;
            split2(v.x, h4.x, l4.x);
            split2(v.y, h4.y, l4.y);
            split2(v.z, h4.z, l4.z);
            split2(v.w, h4.w, l4.w);
            *(ushort4*)&xs_hi[r][kq] = h4;
            *(ushort4*)&xs_lo[r][kq] = l4;
        }
        __syncthreads();
        bf16x8 a_hi = *(const bf16x8*)&xs_hi[wid * 16 + arow][kgrp * 8];
        bf16x8 a_lo = *(const bf16x8*)&xs_lo[wid * 16 + arow][kgrp * 8];
        #pragma unroll
        for (int ct = 0; ct < 8; ++ct) {
            const size_t wof = (size_t)(ct * 16 + arow) * K + k0 + kgrp * 8;
            bf16x8 b_hi = *(const bf16x8*)&wt_hi[wof];
            bf16x8 b_lo = *(const bf16x8*)&wt_lo[wof];
            acc[ct] = __builtin_amdgcn_mfma_f32_16x16x32_bf16(a_hi, b_hi, acc[ct], 0, 0, 0);
            acc[ct] = __builtin_amdgcn_mfma_f32_16x16x32_bf16(a_hi, b_lo, acc[ct], 0, 0, 0);
            acc[ct] = __builtin_amdgcn_mfma_f32_16x16x32_bf16(a_lo, b_hi, acc[ct], 0, 0, 0);
        }
        __syncthreads();
    }
    #pragma unroll
    for (int ct = 0; ct < 8; ++ct) {
        #pragma unroll
        for (int r = 0; r < 4; ++r) {
            int row = row0 + wid * 16 + kgrp * 4 + r;
            if (row < n) O[(size_t)row * 128 + ct * 16 + arow] = f2bf(acc[ct][r]);
        }
    }
}

// ---------------------------------------------------------------------------
// Aggregation over bf16 rows: one wave per node, 1 uint (2 bf16) per lane.
// 8-deep edge unroll: 8 independent row-gathers in flight per wave.
// ---------------------------------------------------------------------------
#define AGG_GATHER(P, U) \
    uint U = src[(size_t)__float_as_int((P).x) * 64 + lane];
#define AGG_FMA(P, U) \
    acc.x += (P).y * __uint_as_float((U) << 16); \
    acc.y += (P).y * __uint_as_float((U) & 0xffff0000u);

__device__ inline float2 agg_row(const int* rowptr, const float2* pairs,
                                 const uint* src, int node, int lane) {
    const int start = rowptr[node];
    const int end = rowptr[node + 1];
    float2 acc = make_float2(0.f, 0.f);
    int j = start;
    for (; j + 7 < end; j += 8) {
        float2 p0 = pairs[j],     p1 = pairs[j + 1], p2 = pairs[j + 2], p3 = pairs[j + 3];
        float2 p4 = pairs[j + 4], p5 = pairs[j + 5], p6 = pairs[j + 6], p7 = pairs[j + 7];
        AGG_GATHER(p0, u0) AGG_GATHER(p1, u1) AGG_GATHER(p2, u2) AGG_GATHER(p3, u3)
        AGG_GATHER(p4, u4) AGG_GATHER(p5, u5) AGG_GATHER(p6, u6) AGG_GATHER(p7, u7)
        AGG_FMA(p0, u0) AGG_FMA(p1, u1) AGG_FMA(p2, u2) AGG_FMA(p3, u3)
        AGG_FMA(p4, u4) AGG_FMA(p5, u5) AGG_FMA(p6, u6) AGG_FMA(p7, u7)
    }
    for (; j + 1 < end; j += 2) {
        float2 p0 = pairs[j], p1 = pairs[j + 1];
        AGG_GATHER(p0, u0) AGG_GATHER(p1, u1)
        AGG_FMA(p0, u0) AGG_FMA(p1, u1)
    }
    if (j < end) {
        float2 p0 = pairs[j];
        AGG_GATHER(p0, u0)
        AGG_FMA(p0, u0)
    }
    return acc;
}

__global__ __launch_bounds__(256) void agg1_kernel(const int* __restrict__ rowptr,
                                                   const float2* __restrict__ pairs,
                                                   const uint* __restrict__ h0,
                                                   const float* __restrict__ b1,
                                                   float* __restrict__ h, int n) {
    const int lane = threadIdx.x & 63;
    const int node = blockIdx.x * 4 + (threadIdx.x >> 6);
    if (node >= n) return;
    float2 acc = agg_row(rowptr, pairs, h0, node, lane);
    float2 bb = *(const float2*)&b1[2 * lane];
    acc.x += bb.x;
    acc.y += bb.y;
    acc.x = acc.x > 0.f ? acc.x : expm1f(acc.x);
    acc.y = acc.y > 0.f ? acc.y : expm1f(acc.y);
    *(float2*)&h[(size_t)node * 128 + 2 * lane] = acc;
}

__global__ __launch_bounds__(256) void agg2_kernel(const int* __restrict__ rowptr,
                                                   const float2* __restrict__ pairs,
                                                   const uint* __restrict__ hcat,
                                                   const float* __restrict__ bmu,
                                                   const float* __restrict__ bls,
                                                   float* __restrict__ out, int n) {
    const int lane = threadIdx.x & 63;
    const int node = blockIdx.x * 4 + (threadIdx.x >> 6);
    if (node >= n) return;
    float2 acc = agg_row(rowptr, pairs, hcat, node, lane);
    const int ci = 2 * lane;
    if (lane < 32) {
        acc.x += bmu[ci];
        acc.y += bmu[ci + 1];
        *(float2*)&out[(size_t)node * 64 + ci] = acc;
    } else {
        acc.x += bls[ci - 64];
        acc.y += bls[ci - 63];
        *(float2*)&out[(size_t)n * 64 + (size_t)node * 64 + (ci - 64)] = acc;
    }
}

// ---------------------------------------------------------------------------

extern "C" void kernel_launch(void* const* d_in, const int* in_sizes, int n_in,
                              void* d_out, int out_size, void* d_ws, size_t ws_size,
                              hipStream_t stream) {
    const float* x   = (const float*)d_in[0];
    const int*   ei  = (const int*)d_in[1];
    const float* ew  = (const float*)d_in[2];
    const float* W1  = (const float*)d_in[3];
    const float* b1  = (const float*)d_in[4];
    const float* Wmu = (const float*)d_in[5];
    const float* bmu = (const float*)d_in[6];
    const float* Wls = (const float*)d_in[7];
    const float* bls = (const float*)d_in[8];
    float*       out = (float*)d_out;

    const int n = in_sizes[0] / IN_C;     // 50000
    const int e = in_sizes[2];            // 1600000
    const int nnz = e + n;
    const int nchunks = (nnz + CHUNK - 1) / CHUNK;
    const unsigned bmag = (unsigned)(((unsigned long long)NB << 32) / (unsigned)n + 1);

    char* ws = (char*)d_ws;
    size_t off = 0;
    auto alloc = [&](size_t bytes) -> void* {
        void* p = ws + off;
        off = (off + bytes + 255) & ~(size_t)255;
        return p;
    };
    int*    hist   = (int*)   alloc((size_t)nchunks * NB * 4);
    int*    totals = (int*)   alloc(NB * 4);
    int*    bbase  = (int*)   alloc((NB + 1) * 4);
    int*    rowptr = (int*)   alloc((size_t)(n + 1) * 4);
    float*  dinv   = (float*) alloc((size_t)n * 4);
    float2* pairs  = (float2*)alloc((size_t)nnz * 8);
    ushort* wt1_hi = (ushort*)alloc((size_t)128 * IN_C * 2);
    ushort* wt1_lo = (ushort*)alloc((size_t)128 * IN_C * 2);
    ushort* wt2_hi = (ushort*)alloc((size_t)128 * HID * 2);
    ushort* wt2_lo = (ushort*)alloc((size_t)128 * HID * 2);
    char*   shared_base = (char*)alloc((size_t)nnz * 12 + 1024);
    float2* ptmp = (float2*)shared_base;
    int*    dtmp = (int*)(shared_base + (size_t)nnz * 8);
    ushort* h0   = (ushort*)shared_base;        // [n][128] bf16
    ushort* hcat = (ushort*)shared_base;        // reuses h0
    (void)ws_size;
    float* hbuf = out;   // layer-1 activations (fp32) live in d_out

    histA_kernel<<<nchunks, 256, 0, stream>>>(ei, hist, e, n, bmag);
    scanB1_kernel<<<NB, 256, 0, stream>>>(hist, totals, nchunks);
    scanB2_kernel<<<1, 256, 0, stream>>>(totals, bbase);
    scatterC_kernel<<<nchunks, 256, 0, stream>>>(ei, ew, hist, bbase, ptmp, dtmp, e, n, bmag);
    bucketD_kernel<<<NB, 256, 0, stream>>>(ptmp, dtmp, bbase, pairs, rowptr, dinv, n, nnz);
    fixup_kernel<<<(nnz + 255) / 256, 256, 0, stream>>>(pairs, dinv, nnz);
    wsplit_kernel<<<(IN_C * 128 + 255) / 256, 256, 0, stream>>>(W1, nullptr, wt1_hi, wt1_lo, IN_C, 0);
    wsplit_kernel<<<(HID * 128 + 255) / 256, 256, 0, stream>>>(Wmu, Wls, wt2_hi, wt2_lo, HID, 1);

    gemm_mfma_kernel<IN_C><<<(n + 63) / 64, 256, 0, stream>>>(x, wt1_hi, wt1_lo, h0, n);
    agg1_kernel<<<(n + 3) / 4, 256, 0, stream>>>(rowptr, pairs, (const uint*)h0, b1, hbuf, n);
    gemm_mfma_kernel<HID><<<(n + 63) / 64, 256, 0, stream>>>(hbuf, wt2_hi, wt2_lo, hcat, n);
    agg2_kernel<<<(n + 3) / 4, 256, 0, stream>>>(rowptr, pairs, (const uint*)hcat, bmu, bls, out, n);
}

// Round 8
// 241.382 us; speedup vs baseline: 2.7075x; 1.2418x over previous
//
#include <hip/hip_runtime.h>
#include <stdint.h>
#include <math.h>

#define IN_C 256
#define HID 128
#define OUT_C 64
#define NB 256        // dst buckets
#define CHUNK 4096    // edges per chunk in hist/scatter phases

typedef __attribute__((ext_vector_type(8))) short bf16x8;
typedef __attribute__((ext_vector_type(4))) float f32x4;

__device__ inline ushort f2bf(float f) {
    uint u = __float_as_uint(f);
    u += 0x7fff + ((u >> 16) & 1);           // RNE
    return (ushort)(u >> 16);
}
__device__ inline void split2(float f, ushort& h, ushort& l) {
    h = f2bf(f);
    float fh = __uint_as_float(((uint)h) << 16);
    l = f2bf(f - fh);
}

// ---------------------------------------------------------------------------
// Preprocessing: bucket-sort CSR build, no global atomics.
// ---------------------------------------------------------------------------
__global__ __launch_bounds__(256) void histA_kernel(const int* __restrict__ ei,
                                                    int* __restrict__ hist,
                                                    int e, int n, unsigned bmag) {
    __shared__ int h[NB];
    const int t = threadIdx.x;
    h[t] = 0;
    __syncthreads();
    const int base = blockIdx.x * CHUNK;
    #pragma unroll
    for (int i = 0; i < CHUNK / 256; ++i) {
        int j = base + t + i * 256;
        int d = -1;
        if (j < e) d = ei[e + j];
        else if (j < e + n) d = j - e;          // self-loop
        if (d >= 0) atomicAdd(&h[__umulhi((unsigned)d, bmag)], 1);
    }
    __syncthreads();
    hist[blockIdx.x * NB + t] = h[t];
}

__global__ __launch_bounds__(256) void scanB1_kernel(int* __restrict__ hist,
                                                     int* __restrict__ totals,
                                                     int nchunks) {
    __shared__ int buf[256];
    const int b = blockIdx.x;
    const int t = threadIdx.x;
    int running = 0;
    for (int base = 0; base < nchunks; base += 256) {
        int idx = base + t;
        int v = (idx < nchunks) ? hist[idx * NB + b] : 0;
        buf[t] = v;
        __syncthreads();
        for (int g = 1; g < 256; g <<= 1) {
            int add = (t >= g) ? buf[t - g] : 0;
            __syncthreads();
            buf[t] += add;
            __syncthreads();
        }
        if (idx < nchunks) hist[idx * NB + b] = running + buf[t] - v;
        running += buf[255];
        __syncthreads();
    }
    if (t == 0) totals[b] = running;
}

__global__ __launch_bounds__(256) void scanB2_kernel(const int* __restrict__ totals,
                                                     int* __restrict__ bbase) {
    __shared__ int buf[256];
    const int t = threadIdx.x;
    int v = totals[t];
    buf[t] = v;
    __syncthreads();
    for (int g = 1; g < 256; g <<= 1) {
        int add = (t >= g) ? buf[t - g] : 0;
        __syncthreads();
        buf[t] += add;
        __syncthreads();
    }
    bbase[t] = buf[t] - v;
    if (t == 255) bbase[256] = buf[255];
}

__global__ __launch_bounds__(256) void scatterC_kernel(const int* __restrict__ ei,
                                                       const float* __restrict__ ew,
                                                       const int* __restrict__ hist,
                                                       const int* __restrict__ bbase,
                                                       float2* __restrict__ ptmp,
                                                       int* __restrict__ dtmp,
                                                       int e, int n, unsigned bmag) {
    __shared__ int cur[NB];
    const int t = threadIdx.x;
    cur[t] = bbase[t] + hist[blockIdx.x * NB + t];
    __syncthreads();
    const int base = blockIdx.x * CHUNK;
    #pragma unroll
    for (int i = 0; i < CHUNK / 256; ++i) {
        int j = base + t + i * 256;
        if (j < e) {
            int d = ei[e + j];
            int s = ei[j];
            float w = ew[j];
            int pos = atomicAdd(&cur[__umulhi((unsigned)d, bmag)], 1);
            ptmp[pos] = make_float2(__int_as_float(s), w);
            dtmp[pos] = d;
        } else if (j < e + n) {
            int d = j - e;
            int pos = atomicAdd(&cur[__umulhi((unsigned)d, bmag)], 1);
            ptmp[pos] = make_float2(__int_as_float(d), 1.0f);
            dtmp[pos] = d;
        }
    }
}

__global__ __launch_bounds__(256) void bucketD_kernel(const float2* __restrict__ ptmp,
                                                      const int* __restrict__ dtmp,
                                                      const int* __restrict__ bbase,
                                                      float2* __restrict__ pairs,
                                                      int* __restrict__ rowptr,
                                                      float* __restrict__ dinv,
                                                      int n, int nnz) {
    const int b = blockIdx.x;
    const int t = threadIdx.x;
    const int lo = (b * n + NB - 1) / NB;
    const int hi = ((b + 1) * n + NB - 1) / NB;
    const int nn = hi - lo;                       // <= 224
    __shared__ int   cnt[224];
    __shared__ float deg[224];
    __shared__ float dv[224];
    __shared__ int   cur2[224];
    __shared__ int   sb[256];
    if (t < nn) { cnt[t] = 0; deg[t] = 0.f; }
    __syncthreads();
    const int s0 = bbase[b], s1 = bbase[b + 1];
    for (int k = s0 + t; k < s1; k += 256) {
        int dl = dtmp[k] - lo;
        atomicAdd(&cnt[dl], 1);
        atomicAdd(&deg[dl], ptmp[k].y);
    }
    __syncthreads();
    int v = (t < nn) ? cnt[t] : 0;
    sb[t] = v;
    __syncthreads();
    for (int g = 1; g < 256; g <<= 1) {
        int add = (t >= g) ? sb[t - g] : 0;
        __syncthreads();
        sb[t] += add;
        __syncthreads();
    }
    if (t < nn) {
        int excl = sb[t] - v;
        int node = lo + t;
        float di = rsqrtf(deg[t]);
        rowptr[node] = s0 + excl;
        dinv[node] = di;
        dv[t] = di;
        cur2[t] = s0 + excl;
    }
    __syncthreads();
    for (int k = s0 + t; k < s1; k += 256) {
        int dl = dtmp[k] - lo;
        float2 p = ptmp[k];
        int pos = atomicAdd(&cur2[dl], 1);
        pairs[pos] = make_float2(p.x, p.y * dv[dl]);
    }
    if (b == NB - 1 && t == 0) rowptr[n] = nnz;
}

__global__ void fixup_kernel(float2* __restrict__ pairs, const float* __restrict__ dinv,
                             int nnz) {
    int k = blockIdx.x * blockDim.x + threadIdx.x;
    if (k < nnz) {
        float2 p = pairs[k];
        p.y *= dinv[__float_as_int(p.x)];
        pairs[k] = p;
    }
}

// ---------------------------------------------------------------------------
// Weight split: logical W[k][c] (c in [0,128)) -> wt_hi/wt_lo [c][Kdim] bf16
// ---------------------------------------------------------------------------
__global__ void wsplit_kernel(const float* __restrict__ Wa, const float* __restrict__ Wb,
                              ushort* __restrict__ hi, ushort* __restrict__ lo,
                              int Kdim, int splitcols) {
    int idx = blockIdx.x * blockDim.x + threadIdx.x;
    if (idx >= Kdim * 128) return;
    int k = idx >> 7, c = idx & 127;
    float w = splitcols ? ((c < 64) ? Wa[k * 64 + c] : Wb[k * 64 + (c - 64)])
                        : Wa[k * 128 + c];
    ushort h, l;
    split2(w, h, l);
    hi[(size_t)c * Kdim + k] = h;
    lo[(size_t)c * Kdim + k] = l;
}

// ---------------------------------------------------------------------------
// MFMA GEMM: O[n][128](bf16) = X[n][K](f32) @ W[K][128], bf16 hi/lo split.
// Block: 256 thr / 4 waves; tile 64 rows x 128 cols. Wave (wr, wc) owns
// 32 rows x 64 cols. W k-slice staged in LDS per k-step (padded rows),
// X staged hi/lo in LDS. All global loads issued before any use.
// ---------------------------------------------------------------------------
template <int K>
__global__ __launch_bounds__(256) void gemm_mfma_kernel(const float* __restrict__ X,
                                                        const ushort* __restrict__ wt_hi,
                                                        const ushort* __restrict__ wt_lo,
                                                        ushort* __restrict__ O, int n) {
    __shared__ ushort xs_hi[64][40];    // 32 k + pad
    __shared__ ushort xs_lo[64][40];
    __shared__ ushort ws_hi[128][40];   // 128 cols x 32 k + pad
    __shared__ ushort ws_lo[128][40];
    const int tid = threadIdx.x;
    const int wid = tid >> 6;
    const int lane = tid & 63;
    const int arow = lane & 15;
    const int kgrp = lane >> 4;
    const int wr = wid >> 1;            // 0..1 row-half
    const int wc = wid & 1;             // 0..1 col-half
    const int row0 = blockIdx.x * 64;

    const ushort* wsrc = (tid < 128) ? wt_hi : wt_lo;
    const int wcidx = tid & 127;        // col this thread stages

    f32x4 acc[2][4];
    #pragma unroll
    for (int rt = 0; rt < 2; ++rt)
        #pragma unroll
        for (int ct = 0; ct < 4; ++ct) acc[rt][ct] = (f32x4){0.f, 0.f, 0.f, 0.f};

    for (int k0 = 0; k0 < K; k0 += 32) {
        // ---- issue all global loads first (6 per thread) ----
        float4 xv[2];
        #pragma unroll
        for (int i = 0; i < 2; ++i) {
            int idx = tid + i * 256;
            int r = idx >> 3, kq = (idx & 7) * 4;
            int row = row0 + r;
            xv[i] = (row < n) ? *(const float4*)&X[(size_t)row * K + k0 + kq]
                              : make_float4(0.f, 0.f, 0.f, 0.f);
        }
        uint4 wv[4];
        #pragma unroll
        for (int q = 0; q < 4; ++q)
            wv[q] = *(const uint4*)&wsrc[(size_t)wcidx * K + k0 + q * 8];
        // ---- split X, write LDS ----
        #pragma unroll
        for (int i = 0; i < 2; ++i) {
            int idx = tid + i * 256;
            int r = idx >> 3, kq = (idx & 7) * 4;
            ushort4 h4, l4;
            split2(xv[i].x, h4.x, l4.x);
            split2(xv[i].y, h4.y, l4.y);
            split2(xv[i].z, h4.z, l4.z);
            split2(xv[i].w, h4.w, l4.w);
            *(ushort4*)&xs_hi[r][kq] = h4;
            *(ushort4*)&xs_lo[r][kq] = l4;
        }
        {
            ushort (*wdst)[40] = (tid < 128) ? ws_hi : ws_lo;
            #pragma unroll
            for (int q = 0; q < 4; ++q)
                *(uint4*)&wdst[wcidx][q * 8] = wv[q];
        }
        __syncthreads();
        // ---- fragments + MFMA ----
        bf16x8 a_hi[2], a_lo[2];
        #pragma unroll
        for (int rt = 0; rt < 2; ++rt) {
            a_hi[rt] = *(const bf16x8*)&xs_hi[wr * 32 + rt * 16 + arow][kgrp * 8];
            a_lo[rt] = *(const bf16x8*)&xs_lo[wr * 32 + rt * 16 + arow][kgrp * 8];
        }
        #pragma unroll
        for (int ct = 0; ct < 4; ++ct) {
            int col = wc * 64 + ct * 16 + arow;
            bf16x8 b_hi = *(const bf16x8*)&ws_hi[col][kgrp * 8];
            bf16x8 b_lo = *(const bf16x8*)&ws_lo[col][kgrp * 8];
            #pragma unroll
            for (int rt = 0; rt < 2; ++rt) {
                acc[rt][ct] = __builtin_amdgcn_mfma_f32_16x16x32_bf16(a_hi[rt], b_hi, acc[rt][ct], 0, 0, 0);
                acc[rt][ct] = __builtin_amdgcn_mfma_f32_16x16x32_bf16(a_hi[rt], b_lo, acc[rt][ct], 0, 0, 0);
                acc[rt][ct] = __builtin_amdgcn_mfma_f32_16x16x32_bf16(a_lo[rt], b_hi, acc[rt][ct], 0, 0, 0);
            }
        }
        __syncthreads();
    }
    #pragma unroll
    for (int rt = 0; rt < 2; ++rt)
        #pragma unroll
        for (int ct = 0; ct < 4; ++ct)
            #pragma unroll
            for (int r = 0; r < 4; ++r) {
                int row = row0 + wr * 32 + rt * 16 + kgrp * 4 + r;
                int col = wc * 64 + ct * 16 + arow;
                if (row < n) O[(size_t)row * 128 + col] = f2bf(acc[rt][ct][r]);
            }
}

// ---------------------------------------------------------------------------
// Aggregation over bf16 rows: one wave per node, 1 uint (2 bf16) per lane.
// 8-deep edge unroll for MLP.
// ---------------------------------------------------------------------------
#define AGG_GATHER(P, U) \
    uint U = src[(size_t)__float_as_int((P).x) * 64 + lane];
#define AGG_FMA(P, U) \
    acc.x += (P).y * __uint_as_float((U) << 16); \
    acc.y += (P).y * __uint_as_float((U) & 0xffff0000u);

__device__ inline float2 agg_row(const int* rowptr, const float2* pairs,
                                 const uint* src, int node, int lane) {
    const int start = rowptr[node];
    const int end = rowptr[node + 1];
    float2 acc = make_float2(0.f, 0.f);
    int j = start;
    for (; j + 7 < end; j += 8) {
        float2 p0 = pairs[j],     p1 = pairs[j + 1], p2 = pairs[j + 2], p3 = pairs[j + 3];
        float2 p4 = pairs[j + 4], p5 = pairs[j + 5], p6 = pairs[j + 6], p7 = pairs[j + 7];
        AGG_GATHER(p0, u0) AGG_GATHER(p1, u1) AGG_GATHER(p2, u2) AGG_GATHER(p3, u3)
        AGG_GATHER(p4, u4) AGG_GATHER(p5, u5) AGG_GATHER(p6, u6) AGG_GATHER(p7, u7)
        AGG_FMA(p0, u0) AGG_FMA(p1, u1) AGG_FMA(p2, u2) AGG_FMA(p3, u3)
        AGG_FMA(p4, u4) AGG_FMA(p5, u5) AGG_FMA(p6, u6) AGG_FMA(p7, u7)
    }
    for (; j + 1 < end; j += 2) {
        float2 p0 = pairs[j], p1 = pairs[j + 1];
        AGG_GATHER(p0, u0) AGG_GATHER(p1, u1)
        AGG_FMA(p0, u0) AGG_FMA(p1, u1)
    }
    if (j < end) {
        float2 p0 = pairs[j];
        AGG_GATHER(p0, u0)
        AGG_FMA(p0, u0)
    }
    return acc;
}

__global__ __launch_bounds__(256) void agg1_kernel(const int* __restrict__ rowptr,
                                                   const float2* __restrict__ pairs,
                                                   const uint* __restrict__ h0,
                                                   const float* __restrict__ b1,
                                                   float* __restrict__ h, int n) {
    const int lane = threadIdx.x & 63;
    const int node = blockIdx.x * 4 + (threadIdx.x >> 6);
    if (node >= n) return;
    float2 acc = agg_row(rowptr, pairs, h0, node, lane);
    float2 bb = *(const float2*)&b1[2 * lane];
    acc.x += bb.x;
    acc.y += bb.y;
    acc.x = acc.x > 0.f ? acc.x : expm1f(acc.x);
    acc.y = acc.y > 0.f ? acc.y : expm1f(acc.y);
    *(float2*)&h[(size_t)node * 128 + 2 * lane] = acc;
}

__global__ __launch_bounds__(256) void agg2_kernel(const int* __restrict__ rowptr,
                                                   const float2* __restrict__ pairs,
                                                   const uint* __restrict__ hcat,
                                                   const float* __restrict__ bmu,
                                                   const float* __restrict__ bls,
                                                   float* __restrict__ out, int n) {
    const int lane = threadIdx.x & 63;
    const int node = blockIdx.x * 4 + (threadIdx.x >> 6);
    if (node >= n) return;
    float2 acc = agg_row(rowptr, pairs, hcat, node, lane);
    const int ci = 2 * lane;
    if (lane < 32) {
        acc.x += bmu[ci];
        acc.y += bmu[ci + 1];
        *(float2*)&out[(size_t)node * 64 + ci] = acc;
    } else {
        acc.x += bls[ci - 64];
        acc.y += bls[ci - 63];
        *(float2*)&out[(size_t)n * 64 + (size_t)node * 64 + (ci - 64)] = acc;
    }
}

// ---------------------------------------------------------------------------

extern "C" void kernel_launch(void* const* d_in, const int* in_sizes, int n_in,
                              void* d_out, int out_size, void* d_ws, size_t ws_size,
                              hipStream_t stream) {
    const float* x   = (const float*)d_in[0];
    const int*   ei  = (const int*)d_in[1];
    const float* ew  = (const float*)d_in[2];
    const float* W1  = (const float*)d_in[3];
    const float* b1  = (const float*)d_in[4];
    const float* Wmu = (const float*)d_in[5];
    const float* bmu = (const float*)d_in[6];
    const float* Wls = (const float*)d_in[7];
    const float* bls = (const float*)d_in[8];
    float*       out = (float*)d_out;

    const int n = in_sizes[0] / IN_C;     // 50000
    const int e = in_sizes[2];            // 1600000
    const int nnz = e + n;
    const int nchunks = (nnz + CHUNK - 1) / CHUNK;
    const unsigned bmag = (unsigned)(((unsigned long long)NB << 32) / (unsigned)n + 1);

    char* ws = (char*)d_ws;
    size_t off = 0;
    auto alloc = [&](size_t bytes) -> void* {
        void* p = ws + off;
        off = (off + bytes + 255) & ~(size_t)255;
        return p;
    };
    int*    hist   = (int*)   alloc((size_t)nchunks * NB * 4);
    int*    totals = (int*)   alloc(NB * 4);
    int*    bbase  = (int*)   alloc((NB + 1) * 4);
    int*    rowptr = (int*)   alloc((size_t)(n + 1) * 4);
    float*  dinv   = (float*) alloc((size_t)n * 4);
    float2* pairs  = (float2*)alloc((size_t)nnz * 8);
    ushort* wt1_hi = (ushort*)alloc((size_t)128 * IN_C * 2);
    ushort* wt1_lo = (ushort*)alloc((size_t)128 * IN_C * 2);
    ushort* wt2_hi = (ushort*)alloc((size_t)128 * HID * 2);
    ushort* wt2_lo = (ushort*)alloc((size_t)128 * HID * 2);
    char*   shared_base = (char*)alloc((size_t)nnz * 12 + 1024);
    float2* ptmp = (float2*)shared_base;
    int*    dtmp = (int*)(shared_base + (size_t)nnz * 8);
    ushort* h0   = (ushort*)shared_base;        // [n][128] bf16
    ushort* hcat = (ushort*)shared_base;        // reuses h0
    (void)ws_size;
    float* hbuf = out;   // layer-1 activations (fp32) live in d_out

    histA_kernel<<<nchunks, 256, 0, stream>>>(ei, hist, e, n, bmag);
    scanB1_kernel<<<NB, 256, 0, stream>>>(hist, totals, nchunks);
    scanB2_kernel<<<1, 256, 0, stream>>>(totals, bbase);
    scatterC_kernel<<<nchunks, 256, 0, stream>>>(ei, ew, hist, bbase, ptmp, dtmp, e, n, bmag);
    bucketD_kernel<<<NB, 256, 0, stream>>>(ptmp, dtmp, bbase, pairs, rowptr, dinv, n, nnz);
    fixup_kernel<<<(nnz + 255) / 256, 256, 0, stream>>>(pairs, dinv, nnz);
    wsplit_kernel<<<(IN_C * 128 + 255) / 256, 256, 0, stream>>>(W1, nullptr, wt1_hi, wt1_lo, IN_C, 0);
    wsplit_kernel<<<(HID * 128 + 255) / 256, 256, 0, stream>>>(Wmu, Wls, wt2_hi, wt2_lo, HID, 1);

    gemm_mfma_kernel<IN_C><<<(n + 63) / 64, 256, 0, stream>>>(x, wt1_hi, wt1_lo, h0, n);
    agg1_kernel<<<(n + 3) / 4, 256, 0, stream>>>(rowptr, pairs, (const uint*)h0, b1, hbuf, n);
    gemm_mfma_kernel<HID><<<(n + 63) / 64, 256, 0, stream>>>(hbuf, wt2_hi, wt2_lo, hcat, n);
    agg2_kernel<<<(n + 3) / 4, 256, 0, stream>>>(rowptr, pairs, (const uint*)hcat, bmu, bls, out, n);
}

// Round 9
// 228.131 us; speedup vs baseline: 2.8648x; 1.0581x over previous
//
#include <hip/hip_runtime.h>
#include <stdint.h>
#include <math.h>

#define IN_C 256
#define HID 128
#define OUT_C 64
#define NB 256        // dst buckets
#define CHUNK 4096    // edges per chunk in hist/scatter phases

typedef __attribute__((ext_vector_type(8))) short bf16x8;
typedef __attribute__((ext_vector_type(4))) float f32x4;

__device__ inline ushort f2bf(float f) {
    uint u = __float_as_uint(f);
    u += 0x7fff + ((u >> 16) & 1);           // RNE
    return (ushort)(u >> 16);
}
__device__ inline void split2(float f, ushort& h, ushort& l) {
    h = f2bf(f);
    float fh = __uint_as_float(((uint)h) << 16);
    l = f2bf(f - fh);
}

// ---------------------------------------------------------------------------
// prepA: fused {histA | wsplit W1 | wsplit W2} via blockIdx branch.
// ---------------------------------------------------------------------------
__global__ __launch_bounds__(256) void prepA_kernel(const int* __restrict__ ei,
                                                    int* __restrict__ hist,
                                                    int e, int n, unsigned bmag,
                                                    const float* __restrict__ W1,
                                                    const float* __restrict__ Wmu,
                                                    const float* __restrict__ Wls,
                                                    ushort* __restrict__ wt1_hi,
                                                    ushort* __restrict__ wt1_lo,
                                                    ushort* __restrict__ wt2_hi,
                                                    ushort* __restrict__ wt2_lo,
                                                    int nchunks) {
    __shared__ int h[NB];
    const int b = blockIdx.x;
    const int t = threadIdx.x;
    if (b < nchunks) {
        h[t] = 0;
        __syncthreads();
        const int base = b * CHUNK;
        #pragma unroll
        for (int i = 0; i < CHUNK / 256; ++i) {
            int j = base + t + i * 256;
            int d = -1;
            if (j < e) d = ei[e + j];
            else if (j < e + n) d = j - e;          // self-loop
            if (d >= 0) atomicAdd(&h[__umulhi((unsigned)d, bmag)], 1);
        }
        __syncthreads();
        hist[b * NB + t] = h[t];
    } else if (b < nchunks + 128) {
        int idx = (b - nchunks) * 256 + t;          // [0, 32768)
        int k = idx >> 7, c = idx & 127;
        ushort hh, ll;
        split2(W1[k * 128 + c], hh, ll);
        wt1_hi[(size_t)c * IN_C + k] = hh;
        wt1_lo[(size_t)c * IN_C + k] = ll;
    } else {
        int idx = (b - nchunks - 128) * 256 + t;    // [0, 16384)
        int k = idx >> 7, c = idx & 127;
        float w = (c < 64) ? Wmu[k * 64 + c] : Wls[k * 64 + (c - 64)];
        ushort hh, ll;
        split2(w, hh, ll);
        wt2_hi[(size_t)c * HID + k] = hh;
        wt2_lo[(size_t)c * HID + k] = ll;
    }
}

// ---------------------------------------------------------------------------
// scans (unchanged)
// ---------------------------------------------------------------------------
__global__ __launch_bounds__(256) void scanB1_kernel(int* __restrict__ hist,
                                                     int* __restrict__ totals,
                                                     int nchunks) {
    __shared__ int buf[256];
    const int b = blockIdx.x;
    const int t = threadIdx.x;
    int running = 0;
    for (int base = 0; base < nchunks; base += 256) {
        int idx = base + t;
        int v = (idx < nchunks) ? hist[idx * NB + b] : 0;
        buf[t] = v;
        __syncthreads();
        for (int g = 1; g < 256; g <<= 1) {
            int add = (t >= g) ? buf[t - g] : 0;
            __syncthreads();
            buf[t] += add;
            __syncthreads();
        }
        if (idx < nchunks) hist[idx * NB + b] = running + buf[t] - v;
        running += buf[255];
        __syncthreads();
    }
    if (t == 0) totals[b] = running;
}

__global__ __launch_bounds__(256) void scanB2_kernel(const int* __restrict__ totals,
                                                     int* __restrict__ bbase) {
    __shared__ int buf[256];
    const int t = threadIdx.x;
    int v = totals[t];
    buf[t] = v;
    __syncthreads();
    for (int g = 1; g < 256; g <<= 1) {
        int add = (t >= g) ? buf[t - g] : 0;
        __syncthreads();
        buf[t] += add;
        __syncthreads();
    }
    bbase[t] = buf[t] - v;
    if (t == 255) bbase[256] = buf[255];
}

// ---------------------------------------------------------------------------
// MFMA GEMM body: O[n][128](bf16) = X[n][K](f32) @ W[K][128], bf16 hi/lo
// split. 4 waves, tile 64x128; wave (wr,wc) owns 32x64. Optional per-row
// output scale (dinv fold for layer 2).
// ---------------------------------------------------------------------------
template <int K, bool SCALE>
__device__ __forceinline__ void gemm_body(const float* __restrict__ X,
                                          const ushort* __restrict__ wt_hi,
                                          const ushort* __restrict__ wt_lo,
                                          ushort* __restrict__ O, int n,
                                          const float* __restrict__ rowscale,
                                          int blk, char* smem) {
    ushort (*xs_hi)[40] = (ushort(*)[40])(smem);            // 64 x 40 x 2B
    ushort (*xs_lo)[40] = (ushort(*)[40])(smem + 5120);
    ushort (*ws_hi)[40] = (ushort(*)[40])(smem + 10240);    // 128 x 40 x 2B
    ushort (*ws_lo)[40] = (ushort(*)[40])(smem + 20480);
    const int tid = threadIdx.x;
    const int wid = tid >> 6;
    const int lane = tid & 63;
    const int arow = lane & 15;
    const int kgrp = lane >> 4;
    const int wr = wid >> 1;
    const int wc = wid & 1;
    const int row0 = blk * 64;

    const ushort* wsrc = (tid < 128) ? wt_hi : wt_lo;
    const int wcidx = tid & 127;

    f32x4 acc[2][4];
    #pragma unroll
    for (int rt = 0; rt < 2; ++rt)
        #pragma unroll
        for (int ct = 0; ct < 4; ++ct) acc[rt][ct] = (f32x4){0.f, 0.f, 0.f, 0.f};

    for (int k0 = 0; k0 < K; k0 += 32) {
        float4 xv[2];
        #pragma unroll
        for (int i = 0; i < 2; ++i) {
            int idx = tid + i * 256;
            int r = idx >> 3, kq = (idx & 7) * 4;
            int row = row0 + r;
            xv[i] = (row < n) ? *(const float4*)&X[(size_t)row * K + k0 + kq]
                              : make_float4(0.f, 0.f, 0.f, 0.f);
        }
        uint4 wv[4];
        #pragma unroll
        for (int q = 0; q < 4; ++q)
            wv[q] = *(const uint4*)&wsrc[(size_t)wcidx * K + k0 + q * 8];
        #pragma unroll
        for (int i = 0; i < 2; ++i) {
            int idx = tid + i * 256;
            int r = idx >> 3, kq = (idx & 7) * 4;
            ushort4 h4, l4;
            split2(xv[i].x, h4.x, l4.x);
            split2(xv[i].y, h4.y, l4.y);
            split2(xv[i].z, h4.z, l4.z);
            split2(xv[i].w, h4.w, l4.w);
            *(ushort4*)&xs_hi[r][kq] = h4;
            *(ushort4*)&xs_lo[r][kq] = l4;
        }
        {
            ushort (*wdst)[40] = (tid < 128) ? ws_hi : ws_lo;
            #pragma unroll
            for (int q = 0; q < 4; ++q)
                *(uint4*)&wdst[wcidx][q * 8] = wv[q];
        }
        __syncthreads();
        bf16x8 a_hi[2], a_lo[2];
        #pragma unroll
        for (int rt = 0; rt < 2; ++rt) {
            a_hi[rt] = *(const bf16x8*)&xs_hi[wr * 32 + rt * 16 + arow][kgrp * 8];
            a_lo[rt] = *(const bf16x8*)&xs_lo[wr * 32 + rt * 16 + arow][kgrp * 8];
        }
        #pragma unroll
        for (int ct = 0; ct < 4; ++ct) {
            int col = wc * 64 + ct * 16 + arow;
            bf16x8 b_hi = *(const bf16x8*)&ws_hi[col][kgrp * 8];
            bf16x8 b_lo = *(const bf16x8*)&ws_lo[col][kgrp * 8];
            #pragma unroll
            for (int rt = 0; rt < 2; ++rt) {
                acc[rt][ct] = __builtin_amdgcn_mfma_f32_16x16x32_bf16(a_hi[rt], b_hi, acc[rt][ct], 0, 0, 0);
                acc[rt][ct] = __builtin_amdgcn_mfma_f32_16x16x32_bf16(a_hi[rt], b_lo, acc[rt][ct], 0, 0, 0);
                acc[rt][ct] = __builtin_amdgcn_mfma_f32_16x16x32_bf16(a_lo[rt], b_hi, acc[rt][ct], 0, 0, 0);
            }
        }
        __syncthreads();
    }
    #pragma unroll
    for (int rt = 0; rt < 2; ++rt)
        #pragma unroll
        for (int ct = 0; ct < 4; ++ct)
            #pragma unroll
            for (int r = 0; r < 4; ++r) {
                int row = row0 + wr * 32 + rt * 16 + kgrp * 4 + r;
                int col = wc * 64 + ct * 16 + arow;
                if (row < n) {
                    float v = acc[rt][ct][r];
                    if (SCALE) v *= rowscale[row];
                    O[(size_t)row * 128 + col] = f2bf(v);
                }
            }
}

// ---------------------------------------------------------------------------
// fusedC: blocks [0,gblocks) run gemm1 (x @ W1 -> h0 bf16);
// blocks [gblocks, gblocks+nchunks) run scatterC.
// ---------------------------------------------------------------------------
__global__ __launch_bounds__(256) void fusedC_kernel(const float* __restrict__ X,
                                                     const ushort* __restrict__ wt1_hi,
                                                     const ushort* __restrict__ wt1_lo,
                                                     ushort* __restrict__ h0, int n,
                                                     int gblocks,
                                                     const int* __restrict__ ei,
                                                     const float* __restrict__ ew,
                                                     const int* __restrict__ hist,
                                                     const int* __restrict__ bbase,
                                                     float2* __restrict__ ptmp,
                                                     int* __restrict__ dtmp,
                                                     int e, unsigned bmag) {
    __shared__ char smem[30720];
    const int b = blockIdx.x;
    if (b < gblocks) {
        gemm_body<IN_C, false>(X, wt1_hi, wt1_lo, h0, n, nullptr, b, smem);
    } else {
        int* cur = (int*)smem;
        const int chunk = b - gblocks;
        const int t = threadIdx.x;
        cur[t] = bbase[t] + hist[chunk * NB + t];
        __syncthreads();
        const int base = chunk * CHUNK;
        #pragma unroll
        for (int i = 0; i < CHUNK / 256; ++i) {
            int j = base + t + i * 256;
            if (j < e) {
                int d = ei[e + j];
                int s = ei[j];
                float w = ew[j];
                int pos = atomicAdd(&cur[__umulhi((unsigned)d, bmag)], 1);
                ptmp[pos] = make_float2(__int_as_float(s), w);
                dtmp[pos] = d;
            } else if (j < e + n) {
                int d = j - e;
                int pos = atomicAdd(&cur[__umulhi((unsigned)d, bmag)], 1);
                ptmp[pos] = make_float2(__int_as_float(d), 1.0f);
                dtmp[pos] = d;
            }
        }
    }
}

__global__ __launch_bounds__(256) void gemm2_kernel(const float* __restrict__ X,
                                                    const ushort* __restrict__ wt_hi,
                                                    const ushort* __restrict__ wt_lo,
                                                    ushort* __restrict__ O, int n,
                                                    const float* __restrict__ dinv) {
    __shared__ char smem[30720];
    gemm_body<HID, true>(X, wt_hi, wt_lo, O, n, dinv, blockIdx.x, smem);
}

// ---------------------------------------------------------------------------
// bucketD: per-bucket CSR finalize (count/deg/scan/scatter, dinv[dst] folded
// into val) + tail: scale this bucket's h0 rows by dinv (dinv[src] fold).
// ---------------------------------------------------------------------------
__global__ __launch_bounds__(256) void bucketD_kernel(const float2* __restrict__ ptmp,
                                                      const int* __restrict__ dtmp,
                                                      const int* __restrict__ bbase,
                                                      float2* __restrict__ pairs,
                                                      int* __restrict__ rowptr,
                                                      float* __restrict__ dinv,
                                                      ushort* __restrict__ h0,
                                                      int n, int nnz) {
    const int b = blockIdx.x;
    const int t = threadIdx.x;
    const int lo = (b * n + NB - 1) / NB;
    const int hi = ((b + 1) * n + NB - 1) / NB;
    const int nn = hi - lo;                       // <= 224
    __shared__ int   cnt[224];
    __shared__ float deg[224];
    __shared__ float dv[224];
    __shared__ int   cur2[224];
    __shared__ int   sb[256];
    if (t < nn) { cnt[t] = 0; deg[t] = 0.f; }
    __syncthreads();
    const int s0 = bbase[b], s1 = bbase[b + 1];
    for (int k = s0 + t; k < s1; k += 256) {
        int dl = dtmp[k] - lo;
        atomicAdd(&cnt[dl], 1);
        atomicAdd(&deg[dl], ptmp[k].y);
    }
    __syncthreads();
    int v = (t < nn) ? cnt[t] : 0;
    sb[t] = v;
    __syncthreads();
    for (int g = 1; g < 256; g <<= 1) {
        int add = (t >= g) ? sb[t - g] : 0;
        __syncthreads();
        sb[t] += add;
        __syncthreads();
    }
    if (t < nn) {
        int excl = sb[t] - v;
        int node = lo + t;
        float di = rsqrtf(deg[t]);
        rowptr[node] = s0 + excl;
        dinv[node] = di;
        dv[t] = di;
        cur2[t] = s0 + excl;
    }
    __syncthreads();
    for (int k = s0 + t; k < s1; k += 256) {
        int dl = dtmp[k] - lo;
        float2 p = ptmp[k];
        int pos = atomicAdd(&cur2[dl], 1);
        pairs[pos] = make_float2(p.x, p.y * dv[dl]);
    }
    if (b == NB - 1 && t == 0) rowptr[n] = nnz;
    // ---- tail: h0 rows [lo,hi) *= dinv  (64 lanes x 1 uint per row) ----
    {
        const int l = t & 63;
        for (int r = t >> 6; r < nn; r += 4) {
            float s = dv[r];
            uint* rowp = (uint*)&h0[(size_t)(lo + r) * 128];
            uint u = rowp[l];
            float a = __uint_as_float(u << 16) * s;          // even col
            float c = __uint_as_float(u & 0xffff0000u) * s;  // odd col
            rowp[l] = ((uint)f2bf(c) << 16) | (uint)f2bf(a);
        }
    }
}

// ---------------------------------------------------------------------------
// Aggregation over bf16 rows: one wave per node, 1 uint (2 bf16) per lane.
// 8-deep edge unroll for MLP.
// ---------------------------------------------------------------------------
#define AGG_GATHER(P, U) \
    uint U = src[(size_t)__float_as_int((P).x) * 64 + lane];
#define AGG_FMA(P, U) \
    acc.x += (P).y * __uint_as_float((U) << 16); \
    acc.y += (P).y * __uint_as_float((U) & 0xffff0000u);

__device__ inline float2 agg_row(const int* rowptr, const float2* pairs,
                                 const uint* src, int node, int lane) {
    const int start = rowptr[node];
    const int end = rowptr[node + 1];
    float2 acc = make_float2(0.f, 0.f);
    int j = start;
    for (; j + 7 < end; j += 8) {
        float2 p0 = pairs[j],     p1 = pairs[j + 1], p2 = pairs[j + 2], p3 = pairs[j + 3];
        float2 p4 = pairs[j + 4], p5 = pairs[j + 5], p6 = pairs[j + 6], p7 = pairs[j + 7];
        AGG_GATHER(p0, u0) AGG_GATHER(p1, u1) AGG_GATHER(p2, u2) AGG_GATHER(p3, u3)
        AGG_GATHER(p4, u4) AGG_GATHER(p5, u5) AGG_GATHER(p6, u6) AGG_GATHER(p7, u7)
        AGG_FMA(p0, u0) AGG_FMA(p1, u1) AGG_FMA(p2, u2) AGG_FMA(p3, u3)
        AGG_FMA(p4, u4) AGG_FMA(p5, u5) AGG_FMA(p6, u6) AGG_FMA(p7, u7)
    }
    for (; j + 1 < end; j += 2) {
        float2 p0 = pairs[j], p1 = pairs[j + 1];
        AGG_GATHER(p0, u0) AGG_GATHER(p1, u1)
        AGG_FMA(p0, u0) AGG_FMA(p1, u1)
    }
    if (j < end) {
        float2 p0 = pairs[j];
        AGG_GATHER(p0, u0)
        AGG_FMA(p0, u0)
    }
    return acc;
}

__global__ __launch_bounds__(256) void agg1_kernel(const int* __restrict__ rowptr,
                                                   const float2* __restrict__ pairs,
                                                   const uint* __restrict__ h0,
                                                   const float* __restrict__ b1,
                                                   float* __restrict__ h, int n) {
    const int lane = threadIdx.x & 63;
    const int node = blockIdx.x * 4 + (threadIdx.x >> 6);
    if (node >= n) return;
    float2 acc = agg_row(rowptr, pairs, h0, node, lane);
    float2 bb = *(const float2*)&b1[2 * lane];
    acc.x += bb.x;
    acc.y += bb.y;
    acc.x = acc.x > 0.f ? acc.x : expm1f(acc.x);
    acc.y = acc.y > 0.f ? acc.y : expm1f(acc.y);
    *(float2*)&h[(size_t)node * 128 + 2 * lane] = acc;
}

__global__ __launch_bounds__(256) void agg2_kernel(const int* __restrict__ rowptr,
                                                   const float2* __restrict__ pairs,
                                                   const uint* __restrict__ hcat,
                                                   const float* __restrict__ bmu,
                                                   const float* __restrict__ bls,
                                                   float* __restrict__ out, int n) {
    const int lane = threadIdx.x & 63;
    const int node = blockIdx.x * 4 + (threadIdx.x >> 6);
    if (node >= n) return;
    float2 acc = agg_row(rowptr, pairs, hcat, node, lane);
    const int ci = 2 * lane;
    if (lane < 32) {
        acc.x += bmu[ci];
        acc.y += bmu[ci + 1];
        *(float2*)&out[(size_t)node * 64 + ci] = acc;
    } else {
        acc.x += bls[ci - 64];
        acc.y += bls[ci - 63];
        *(float2*)&out[(size_t)n * 64 + (size_t)node * 64 + (ci - 64)] = acc;
    }
}

// ---------------------------------------------------------------------------

extern "C" void kernel_launch(void* const* d_in, const int* in_sizes, int n_in,
                              void* d_out, int out_size, void* d_ws, size_t ws_size,
                              hipStream_t stream) {
    const float* x   = (const float*)d_in[0];
    const int*   ei  = (const int*)d_in[1];
    const float* ew  = (const float*)d_in[2];
    const float* W1  = (const float*)d_in[3];
    const float* b1  = (const float*)d_in[4];
    const float* Wmu = (const float*)d_in[5];
    const float* bmu = (const float*)d_in[6];
    const float* Wls = (const float*)d_in[7];
    const float* bls = (const float*)d_in[8];
    float*       out = (float*)d_out;

    const int n = in_sizes[0] / IN_C;     // 50000
    const int e = in_sizes[2];            // 1600000
    const int nnz = e + n;
    const int nchunks = (nnz + CHUNK - 1) / CHUNK;
    const int gblocks = (n + 63) / 64;
    const unsigned bmag = (unsigned)(((unsigned long long)NB << 32) / (unsigned)n + 1);

    char* ws = (char*)d_ws;
    size_t off = 0;
    auto alloc = [&](size_t bytes) -> void* {
        void* p = ws + off;
        off = (off + bytes + 255) & ~(size_t)255;
        return p;
    };
    int*    hist   = (int*)   alloc((size_t)nchunks * NB * 4);
    int*    totals = (int*)   alloc(NB * 4);
    int*    bbase  = (int*)   alloc((NB + 1) * 4);
    int*    rowptr = (int*)   alloc((size_t)(n + 1) * 4);
    float*  dinv   = (float*) alloc((size_t)n * 4);
    float2* pairs  = (float2*)alloc((size_t)nnz * 8);
    float2* ptmp   = (float2*)alloc((size_t)nnz * 8);
    int*    dtmp   = (int*)   alloc((size_t)nnz * 4);
    ushort* wt1_hi = (ushort*)alloc((size_t)128 * IN_C * 2);
    ushort* wt1_lo = (ushort*)alloc((size_t)128 * IN_C * 2);
    ushort* wt2_hi = (ushort*)alloc((size_t)128 * HID * 2);
    ushort* wt2_lo = (ushort*)alloc((size_t)128 * HID * 2);
    ushort* h0     = (ushort*)alloc((size_t)n * 128 * 2);   // bf16; hcat reuses
    ushort* hcat   = h0;                                    // dead after agg1
    (void)ws_size;
    float* hbuf = out;   // layer-1 activations (fp32) live in d_out

    prepA_kernel<<<nchunks + 192, 256, 0, stream>>>(ei, hist, e, n, bmag,
                                                    W1, Wmu, Wls,
                                                    wt1_hi, wt1_lo, wt2_hi, wt2_lo, nchunks);
    scanB1_kernel<<<NB, 256, 0, stream>>>(hist, totals, nchunks);
    scanB2_kernel<<<1, 256, 0, stream>>>(totals, bbase);
    fusedC_kernel<<<gblocks + nchunks, 256, 0, stream>>>(x, wt1_hi, wt1_lo, h0, n, gblocks,
                                                         ei, ew, hist, bbase, ptmp, dtmp,
                                                         e, bmag);
    bucketD_kernel<<<NB, 256, 0, stream>>>(ptmp, dtmp, bbase, pairs, rowptr, dinv, h0, n, nnz);
    agg1_kernel<<<(n + 3) / 4, 256, 0, stream>>>(rowptr, pairs, (const uint*)h0, b1, hbuf, n);
    gemm2_kernel<<<gblocks, 256, 0, stream>>>(hbuf, wt2_hi, wt2_lo, hcat, n, dinv);
    agg2_kernel<<<(n + 3) / 4, 256, 0, stream>>>(rowptr, pairs, (const uint*)hcat, bmu, bls, out, n);
}